// Round 21
// baseline (248.233 us; speedup 1.0000x reference)
//
#include <hip/hip_runtime.h>
#include <hip/hip_bf16.h>
#include <stdint.h>

#define DD 256
#define NB 16
#define NN 1024
#define MTOT (NB * NN)  // 16384

typedef __attribute__((ext_vector_type(8))) short short8;
typedef __attribute__((ext_vector_type(4))) float f32x4;

__device__ __forceinline__ ushort f2b(float f) {
  uint32_t u = __float_as_uint(f);
  return (ushort)((u + 0x7fffu + ((u >> 16) & 1u)) >> 16);
}

// Stage a 256x256 fp32 weight matrix into LDS as bf16, XOR-swizzled rows.
__device__ __forceinline__ void stage_weights(const float* __restrict__ W,
                                              ushort* Wl, int tid) {
  for (int i = 0; i < 64; ++i) {
    int idx4 = i * 256 + tid;
    int row = idx4 >> 6;
    int col0 = (idx4 & 63) << 2;
    float4 v = ((const float4*)W)[idx4];
    ushort4 b4;
    b4.x = f2b(v.x); b4.y = f2b(v.y); b4.z = f2b(v.z); b4.w = f2b(v.w);
    int byte = (row * 512 + col0 * 2) ^ ((row & 7) << 4);
    *(ushort4*)((char*)Wl + byte) = b4;
  }
}

// ---------------------------------------------------------------------------
// Fused h/q/k GEMM (round-13, unchanged). Each block owns 64 rows.
__global__ __launch_bounds__(256, 1) void gemm_fused(
    const float* __restrict__ feature, const float* __restrict__ W_w,
    const float* __restrict__ W_b, const float* __restrict__ Q_w,
    const float* __restrict__ Q_b, const float* __restrict__ K_w,
    const float* __restrict__ K_b, ushort* __restrict__ hT,
    ushort* __restrict__ q, ushort* __restrict__ k) {
  __shared__ ushort Wl[256 * 256];  // 128 KB; doubles as Tl transpose buffer
  const int tid = threadIdx.x;
  const int w = tid >> 6, lane = tid & 63, l15 = lane & 15, hi = lane >> 4;
  const int m0 = blockIdx.x * 64 + w * 16;
  const int arow = m0 + l15;

  // ---- h = feature @ W_w^T + W_b ----
  stage_weights(W_w, Wl, tid);
  __syncthreads();

  f32x4 acc[16] = {};
#pragma unroll
  for (int kk = 0; kk < 8; ++kk) {
    const int k0 = kk * 32 + hi * 8;
    const float4* ap = (const float4*)(feature + arow * 256 + k0);
    float4 x = ap[0], y = ap[1];
    short8 a;
    a[0] = (short)f2b(x.x); a[1] = (short)f2b(x.y);
    a[2] = (short)f2b(x.z); a[3] = (short)f2b(x.w);
    a[4] = (short)f2b(y.x); a[5] = (short)f2b(y.y);
    a[6] = (short)f2b(y.z); a[7] = (short)f2b(y.w);
#pragma unroll
    for (int et = 0; et < 16; ++et) {
      int er = et * 16 + l15;
      short8 bf = *(const short8*)((const char*)Wl +
                                   ((er * 512 + k0 * 2) ^ ((er & 7) << 4)));
      acc[et] = __builtin_amdgcn_mfma_f32_16x16x32_bf16(a, bf, acc[et], 0, 0, 0);
    }
  }

  ushort hvals[16][4];
#pragma unroll
  for (int et = 0; et < 16; ++et) {
    float bv = W_b[et * 16 + l15];
#pragma unroll
    for (int r = 0; r < 4; ++r) hvals[et][r] = f2b(acc[et][r] + bv);
  }

  // ---- transpose h into Tl(=Wl) [256][64] ----
  __syncthreads();  // all waves done reading Wl
  ushort* Tl = Wl;
  {
    const int mloc = w * 16 + hi * 4;
#pragma unroll
    for (int et = 0; et < 16; ++et)
#pragma unroll
      for (int r = 0; r < 4; ++r)
        Tl[(et * 16 + l15) * 64 + mloc + r] = hvals[et][r];
  }
  __syncthreads();

  // ---- (a) h A-frags back to registers; (b) hT to global ----
  short8 qa[8];
#pragma unroll
  for (int kk = 0; kk < 8; ++kk) {
    const int k0 = kk * 32 + hi * 8;
#pragma unroll
    for (int j = 0; j < 8; ++j)
      qa[kk][j] = (short)Tl[(k0 + j) * 64 + w * 16 + l15];
  }
  {
    const int bidx = blockIdx.x >> 4;
    const int n0 = (blockIdx.x & 15) * 64;
    ushort* dst = hT + bidx * (256 * 1024) + tid * 1024 + n0;
    const uint4* src = (const uint4*)(Tl + tid * 64);
#pragma unroll
    for (int j = 0; j < 8; ++j) ((uint4*)dst)[j] = src[j];
  }
  __syncthreads();  // Tl reads done before Q_w staging overwrites

  // ---- q = h @ Q_w^T + Q_b ----
  stage_weights(Q_w, Wl, tid);
  __syncthreads();
#pragma unroll
  for (int et = 0; et < 16; ++et) acc[et] = (f32x4){0.f, 0.f, 0.f, 0.f};
#pragma unroll
  for (int kk = 0; kk < 8; ++kk) {
    const int k0 = kk * 32 + hi * 8;
#pragma unroll
    for (int et = 0; et < 16; ++et) {
      int er = et * 16 + l15;
      short8 bf = *(const short8*)((const char*)Wl +
                                   ((er * 512 + k0 * 2) ^ ((er & 7) << 4)));
      acc[et] = __builtin_amdgcn_mfma_f32_16x16x32_bf16(qa[kk], bf, acc[et], 0, 0, 0);
    }
  }
#pragma unroll
  for (int et = 0; et < 16; ++et) {
    int e = et * 16 + l15;
    float bv = Q_b[e];
#pragma unroll
    for (int r = 0; r < 4; ++r)
      q[(m0 + hi * 4 + r) * 256 + e] = f2b(acc[et][r] + bv);
  }
  __syncthreads();  // q-compute reads of Wl done before K_w staging

  // ---- k = h @ K_w^T + K_b ----
  stage_weights(K_w, Wl, tid);
  __syncthreads();
#pragma unroll
  for (int et = 0; et < 16; ++et) acc[et] = (f32x4){0.f, 0.f, 0.f, 0.f};
#pragma unroll
  for (int kk = 0; kk < 8; ++kk) {
    const int k0 = kk * 32 + hi * 8;
#pragma unroll
    for (int et = 0; et < 16; ++et) {
      int er = et * 16 + l15;
      short8 bf = *(const short8*)((const char*)Wl +
                                   ((er * 512 + k0 * 2) ^ ((er & 7) << 4)));
      acc[et] = __builtin_amdgcn_mfma_f32_16x16x32_bf16(qa[kk], bf, acc[et], 0, 0, 0);
    }
  }
#pragma unroll
  for (int et = 0; et < 16; ++et) {
    int e = et * 16 + l15;
    float bv = K_b[e];
#pragma unroll
    for (int r = 0; r < 4; ++r)
      k[(m0 + hi * 4 + r) * 256 + e] = f2b(acc[et][r] + bv);
  }
}

// ---------------------------------------------------------------------------
// Fused attention, KEY-SPLIT: grid 512, each block = 64 q-rows x 512 keys
// (8 tiles). Per-CU staging volume unchanged vs r10, but 2 independent
// barrier groups per CU -> one block's compute fills the other's staging
// stall. Fixed-max softmax makes partials additive: blocks atomicAdd their
// partial O into out (zeroed) and partial l into l_acc; finalize divides.
// Inner tile loop byte-identical to round-10.
#define SM_KT 0        // ushort Kt[64*256]   32768 B
#define SM_HT 32768    // ushort Ht[256*64]   32768 B
#define SM_PL 65536    // ushort Pl[8*16*32]   8192 B
#define SM_M2 73728    // uint   M2[2][128]    1024 B
#define SM_CM 74752    // float  Cm[64]         256 B
#define SM_SZ 75008

// P-buffer swizzle: XOR in bits>=4 keeps 16B blocks intact for ds_read_b128.
__device__ __forceinline__ int pswz(int row, int bytecol) {
  return (row * 64 + bytecol) ^ ((row & 7) << 4) ^ ((row >> 3) << 5);
}

__global__ __launch_bounds__(512, 4) void attn8(
    const ushort* __restrict__ Q, const ushort* __restrict__ Kb,
    const ushort* __restrict__ HT, const int* __restrict__ graph,
    float* __restrict__ out, float* __restrict__ l_acc) {
  __shared__ __align__(16) char smem[SM_SZ];
  ushort* Kt = (ushort*)(smem + SM_KT);
  ushort* Ht = (ushort*)(smem + SM_HT);
  ushort* Pl = (ushort*)(smem + SM_PL);
  uint* M2 = (uint*)(smem + SM_M2);
  float* Cm = (float*)(smem + SM_CM);

  const int tid = threadIdx.x;
  const int w = tid >> 6, lane = tid & 63, l15 = lane & 15, hi = lane >> 4;
  const int wg = w >> 1, half = w & 1;
  // XCD-aware remap: XCD x handles batches {2x, 2x+1}; 64 slots per XCD
  const int hw = blockIdx.x;
  const int slot = hw >> 3;                 // [0,64)
  const int b = (hw & 7) * 2 + (slot >> 5);
  const int rest = slot & 31;
  const int q0 = (rest >> 1) * 64;
  const int ks = rest & 1;                  // key half: [ks*512, ks*512+512)
  const int kt0 = ks * 8;                   // first key tile of this block
  const int qrow_a = q0 + wg * 16 + l15;
  const int qrow_cl = wg * 16 + hi * 4;  // local row base (+r)
  const int* grow_base =
      graph + (b * 1024 + q0 + w * 8) * 1024 + ks * 512 + lane;

  int greg[8];

  // ---- prologue: graph(tile kt0) + Q frags; ballot into M2[0] ----
#pragma unroll
  for (int j = 0; j < 8; ++j) greg[j] = grow_base[j * 1024];

  short8 qf[8];
#pragma unroll
  for (int kk = 0; kk < 8; ++kk)
    qf[kk] = *(const short8*)(Q + (b * 1024 + qrow_a) * 256 + kk * 32 + hi * 8);

#pragma unroll
  for (int j = 0; j < 8; ++j) {
    unsigned long long mm = __ballot(greg[j] != 0);
    if (lane == 0) {
      M2[(w * 8 + j) * 2] = (uint)mm;
      M2[(w * 8 + j) * 2 + 1] = (uint)(mm >> 32);
    }
  }

  float lR[4] = {0.f, 0.f, 0.f, 0.f};  // per-LANE partial row sums
  f32x4 o[16] = {};

  for (int t = 0; t < 8; ++t) {
    const uint* M2c = M2 + (t & 1) * 128;
    uint* M2n = M2 + ((t & 1) ^ 1) * 128;
    const int gk = (kt0 + t) * 64;  // global key offset of this tile

    __syncthreads();
#pragma unroll
    for (int i = 0; i < 4; ++i) {  // stage K tile [64][256]
      int c = i * 512 + tid;
      int krow = c >> 5, col0 = (c & 31) << 3;
      uint4 v = *(const uint4*)(Kb + (b * 1024 + gk + krow) * 256 + col0);
      *(uint4*)((char*)Kt + ((krow * 512 + col0 * 2) ^ ((krow & 7) << 4))) = v;
    }
#pragma unroll
    for (int i = 0; i < 4; ++i) {  // stage H^T tile [256][64]
      int c = i * 512 + tid;
      int drow = c >> 3, col0 = (c & 7) << 3;
      uint4 v = *(const uint4*)(HT + b * (256 * 1024) + drow * 1024 + gk + col0);
      *(uint4*)((char*)Ht + ((drow * 128 + col0 * 2) ^ ((drow & 7) << 4))) = v;
    }
    __syncthreads();

    // issue next tile's graph loads NOW; compute covers the HBM latency
    if (t < 7) {
#pragma unroll
      for (int j = 0; j < 8; ++j) greg[j] = grow_base[j * 1024 + (t + 1) * 64];
    }

    // S = q @ k^T : 16 rows x 32 keys (this wave's half)
    f32x4 s[2] = {};
    __builtin_amdgcn_s_setprio(1);
#pragma unroll
    for (int kk = 0; kk < 8; ++kk) {
#pragma unroll
      for (int nt = 0; nt < 2; ++nt) {
        int krow = half * 32 + nt * 16 + l15;
        short8 kf = *(const short8*)((const char*)Kt +
            ((krow * 512 + (kk * 32 + hi * 8) * 2) ^ ((krow & 7) << 4)));
        s[nt] = __builtin_amdgcn_mfma_f32_16x16x32_bf16(qf[kk], kf, s[nt], 0, 0, 0);
      }
    }
    __builtin_amdgcn_s_setprio(0);

    // scale, leaky, mask, exp — per-lane VALU only
    float p[2][4];
#pragma unroll
    for (int r = 0; r < 4; ++r) {
      uint mw = M2c[(qrow_cl + r) * 2 + half];
      float v0 = s[0][r] * 0.0625f; v0 = (v0 >= 0.f) ? v0 : 0.2f * v0;
      float v1 = s[1][r] * 0.0625f; v1 = (v1 >= 0.f) ? v1 : 0.2f * v1;
      float p0 = ((mw >> l15) & 1u) ? __expf(v0) : 0.f;
      float p1 = ((mw >> (16 + l15)) & 1u) ? __expf(v1) : 0.f;
      p[0][r] = p0; p[1][r] = p1;
      lR[r] += p0 + p1;
    }

    // P (C-layout) -> per-wave LDS -> A-frag layout
    ushort* Pw = Pl + w * 512;
#pragma unroll
    for (int nt = 0; nt < 2; ++nt)
#pragma unroll
      for (int r = 0; r < 4; ++r) {
        int row = hi * 4 + r, col = nt * 16 + l15;
        *(ushort*)((char*)Pw + pswz(row, col * 2)) = f2b(p[nt][r]);
      }
    __asm__ volatile("s_waitcnt lgkmcnt(0)" ::: "memory");
    short8 pa = *(const short8*)((const char*)Pw + pswz(l15, hi * 16));

    // O += P @ H (keys half*32 .. half*32+31)
    __builtin_amdgcn_s_setprio(1);
#pragma unroll
    for (int dt = 0; dt < 16; ++dt) {
      int dcol = dt * 16 + l15;
      short8 hf = *(const short8*)((const char*)Ht +
          ((dcol * 128 + (half * 32 + hi * 8) * 2) ^ ((dcol & 7) << 4)));
      o[dt] = __builtin_amdgcn_mfma_f32_16x16x32_bf16(pa, hf, o[dt], 0, 0, 0);
    }
    __builtin_amdgcn_s_setprio(0);

    // pack next tile's mask into the other M2 buffer
    if (t < 7) {
#pragma unroll
      for (int j = 0; j < 8; ++j) {
        unsigned long long mm = __ballot(greg[j] != 0);
        if (lane == 0) {
          M2n[(w * 8 + j) * 2] = (uint)mm;
          M2n[(w * 8 + j) * 2 + 1] = (uint)(mm >> 32);
        }
      }
    }
  }

  // ---- reduce row sums once (16-lane groups share a row set) ----
#pragma unroll
  for (int r = 0; r < 4; ++r) {
    lR[r] += __shfl_xor(lR[r], 1);
    lR[r] += __shfl_xor(lR[r], 2);
    lR[r] += __shfl_xor(lR[r], 4);
    lR[r] += __shfl_xor(lR[r], 8);
  }

  // ---- combine wave pairs; atomicAdd block partials to global ----
  __syncthreads();  // all tiles done; reuse smem[0,64K) = Kt+Ht as Ob
  float* Ob = (float*)smem;  // 4 pairs x [16][256] fp32 = 64 KB
  if (half == 1) {
#pragma unroll
    for (int dt = 0; dt < 16; ++dt)
#pragma unroll
      for (int r = 0; r < 4; ++r) {
        int row = hi * 4 + r;
        int byte = (row * 1024 + (dt * 16 + l15) * 4) ^ ((row & 15) << 6);
        *(float*)((char*)Ob + wg * 16384 + byte) = o[dt][r];
      }
    if (l15 == 0) {
#pragma unroll
      for (int r = 0; r < 4; ++r)
        Cm[wg * 16 + hi * 4 + r] = lR[r];
    }
  }
  __syncthreads();
  if (half == 0) {
#pragma unroll
    for (int r = 0; r < 4; ++r) {
      int rowl = hi * 4 + r;
      float lpart = lR[r] + Cm[wg * 16 + rowl];
      int orow = b * 1024 + q0 + wg * 16 + rowl;
      if (l15 == 0) atomicAdd(&l_acc[orow], lpart);
#pragma unroll
      for (int dt = 0; dt < 16; ++dt) {
        int byte = (rowl * 1024 + (dt * 16 + l15) * 4) ^ ((rowl & 15) << 6);
        float ob = *(const float*)((const char*)Ob + wg * 16384 + byte);
        atomicAdd(&out[orow * 256 + dt * 16 + l15], o[dt][r] + ob);
      }
    }
  }
}

// ---------------------------------------------------------------------------
// out = relu(out) / l_acc  (relu(o/l) == relu(o)/l since l > 0)
__global__ __launch_bounds__(256) void finalize(float* __restrict__ out,
                                                const float* __restrict__ l_acc) {
  const long i4 = (long)blockIdx.x * blockDim.x + threadIdx.x;
  const long n4 = (long)MTOT * DD / 4;
  const long stride = (long)gridDim.x * blockDim.x;
  for (long i = i4; i < n4; i += stride) {
    float4 v = ((const float4*)out)[i];
    float inv = 1.f / l_acc[(i * 4) >> 8];
    v.x = fmaxf(v.x, 0.f) * inv;
    v.y = fmaxf(v.y, 0.f) * inv;
    v.z = fmaxf(v.z, 0.f) * inv;
    v.w = fmaxf(v.w, 0.f) * inv;
    ((float4*)out)[i] = v;
  }
}

// ---------------------------------------------------------------------------
extern "C" void kernel_launch(void* const* d_in, const int* in_sizes, int n_in,
                              void* d_out, int out_size, void* d_ws,
                              size_t ws_size, hipStream_t stream) {
  const float* feature = (const float*)d_in[0];
  const int* graph = (const int*)d_in[1];
  const float* W_w = (const float*)d_in[2];
  const float* W_b = (const float*)d_in[3];
  const float* Q_w = (const float*)d_in[4];
  const float* Q_b = (const float*)d_in[5];
  const float* K_w = (const float*)d_in[6];
  const float* K_b = (const float*)d_in[7];
  float* out = (float*)d_out;

  ushort* hT = (ushort*)d_ws;         // [B,D,N] bf16   8 MB
  ushort* q = hT + MTOT * DD;         // [B,N,D] bf16   8 MB
  ushort* k = q + MTOT * DD;          // [B,N,D] bf16   8 MB
  float* l_acc = (float*)(k + MTOT * DD);  // [B,N] fp32  64 KB

  hipMemsetAsync(out, 0, (size_t)MTOT * DD * sizeof(float), stream);
  hipMemsetAsync(l_acc, 0, (size_t)MTOT * sizeof(float), stream);
  gemm_fused<<<256, 256, 0, stream>>>(feature, W_w, W_b, Q_w, Q_b, K_w, K_b,
                                      hT, q, k);
  attn8<<<512, 512, 0, stream>>>(q, k, hT, graph, out, l_acc);
  finalize<<<1024, 256, 0, stream>>>(out, l_acc);
}

// Round 22
// 132.971 us; speedup vs baseline: 1.8668x; 1.8668x over previous
//
#include <hip/hip_runtime.h>
#include <hip/hip_bf16.h>
#include <stdint.h>

#define DD 256
#define NB 16
#define NN 1024
#define MTOT (NB * NN)  // 16384

typedef __attribute__((ext_vector_type(8))) short short8;
typedef __attribute__((ext_vector_type(4))) float f32x4;

__device__ __forceinline__ ushort f2b(float f) {
  uint32_t u = __float_as_uint(f);
  return (ushort)((u + 0x7fffu + ((u >> 16) & 1u)) >> 16);
}

// Stage a 256x256 fp32 weight matrix into LDS as bf16, XOR-swizzled rows.
__device__ __forceinline__ void stage_weights(const float* __restrict__ W,
                                              ushort* Wl, int tid) {
  for (int i = 0; i < 64; ++i) {
    int idx4 = i * 256 + tid;
    int row = idx4 >> 6;
    int col0 = (idx4 & 63) << 2;
    float4 v = ((const float4*)W)[idx4];
    ushort4 b4;
    b4.x = f2b(v.x); b4.y = f2b(v.y); b4.z = f2b(v.z); b4.w = f2b(v.w);
    int byte = (row * 512 + col0 * 2) ^ ((row & 7) << 4);
    *(ushort4*)((char*)Wl + byte) = b4;
  }
}

// ---------------------------------------------------------------------------
// Fused h/q/k GEMM (round-13, unchanged). Each block owns 64 rows.
__global__ __launch_bounds__(256, 1) void gemm_fused(
    const float* __restrict__ feature, const float* __restrict__ W_w,
    const float* __restrict__ W_b, const float* __restrict__ Q_w,
    const float* __restrict__ Q_b, const float* __restrict__ K_w,
    const float* __restrict__ K_b, ushort* __restrict__ hT,
    ushort* __restrict__ q, ushort* __restrict__ k) {
  __shared__ ushort Wl[256 * 256];  // 128 KB; doubles as Tl transpose buffer
  const int tid = threadIdx.x;
  const int w = tid >> 6, lane = tid & 63, l15 = lane & 15, hi = lane >> 4;
  const int m0 = blockIdx.x * 64 + w * 16;
  const int arow = m0 + l15;

  // ---- h = feature @ W_w^T + W_b ----
  stage_weights(W_w, Wl, tid);
  __syncthreads();

  f32x4 acc[16] = {};
#pragma unroll
  for (int kk = 0; kk < 8; ++kk) {
    const int k0 = kk * 32 + hi * 8;
    const float4* ap = (const float4*)(feature + arow * 256 + k0);
    float4 x = ap[0], y = ap[1];
    short8 a;
    a[0] = (short)f2b(x.x); a[1] = (short)f2b(x.y);
    a[2] = (short)f2b(x.z); a[3] = (short)f2b(x.w);
    a[4] = (short)f2b(y.x); a[5] = (short)f2b(y.y);
    a[6] = (short)f2b(y.z); a[7] = (short)f2b(y.w);
#pragma unroll
    for (int et = 0; et < 16; ++et) {
      int er = et * 16 + l15;
      short8 bf = *(const short8*)((const char*)Wl +
                                   ((er * 512 + k0 * 2) ^ ((er & 7) << 4)));
      acc[et] = __builtin_amdgcn_mfma_f32_16x16x32_bf16(a, bf, acc[et], 0, 0, 0);
    }
  }

  ushort hvals[16][4];
#pragma unroll
  for (int et = 0; et < 16; ++et) {
    float bv = W_b[et * 16 + l15];
#pragma unroll
    for (int r = 0; r < 4; ++r) hvals[et][r] = f2b(acc[et][r] + bv);
  }

  // ---- transpose h into Tl(=Wl) [256][64] ----
  __syncthreads();  // all waves done reading Wl
  ushort* Tl = Wl;
  {
    const int mloc = w * 16 + hi * 4;
#pragma unroll
    for (int et = 0; et < 16; ++et)
#pragma unroll
      for (int r = 0; r < 4; ++r)
        Tl[(et * 16 + l15) * 64 + mloc + r] = hvals[et][r];
  }
  __syncthreads();

  // ---- (a) h A-frags back to registers; (b) hT to global ----
  short8 qa[8];
#pragma unroll
  for (int kk = 0; kk < 8; ++kk) {
    const int k0 = kk * 32 + hi * 8;
#pragma unroll
    for (int j = 0; j < 8; ++j)
      qa[kk][j] = (short)Tl[(k0 + j) * 64 + w * 16 + l15];
  }
  {
    const int bidx = blockIdx.x >> 4;
    const int n0 = (blockIdx.x & 15) * 64;
    ushort* dst = hT + bidx * (256 * 1024) + tid * 1024 + n0;
    const uint4* src = (const uint4*)(Tl + tid * 64);
#pragma unroll
    for (int j = 0; j < 8; ++j) ((uint4*)dst)[j] = src[j];
  }
  __syncthreads();  // Tl reads done before Q_w staging overwrites

  // ---- q = h @ Q_w^T + Q_b ----
  stage_weights(Q_w, Wl, tid);
  __syncthreads();
#pragma unroll
  for (int et = 0; et < 16; ++et) acc[et] = (f32x4){0.f, 0.f, 0.f, 0.f};
#pragma unroll
  for (int kk = 0; kk < 8; ++kk) {
    const int k0 = kk * 32 + hi * 8;
#pragma unroll
    for (int et = 0; et < 16; ++et) {
      int er = et * 16 + l15;
      short8 bf = *(const short8*)((const char*)Wl +
                                   ((er * 512 + k0 * 2) ^ ((er & 7) << 4)));
      acc[et] = __builtin_amdgcn_mfma_f32_16x16x32_bf16(qa[kk], bf, acc[et], 0, 0, 0);
    }
  }
#pragma unroll
  for (int et = 0; et < 16; ++et) {
    int e = et * 16 + l15;
    float bv = Q_b[e];
#pragma unroll
    for (int r = 0; r < 4; ++r)
      q[(m0 + hi * 4 + r) * 256 + e] = f2b(acc[et][r] + bv);
  }
  __syncthreads();  // q-compute reads of Wl done before K_w staging

  // ---- k = h @ K_w^T + K_b ----
  stage_weights(K_w, Wl, tid);
  __syncthreads();
#pragma unroll
  for (int et = 0; et < 16; ++et) acc[et] = (f32x4){0.f, 0.f, 0.f, 0.f};
#pragma unroll
  for (int kk = 0; kk < 8; ++kk) {
    const int k0 = kk * 32 + hi * 8;
#pragma unroll
    for (int et = 0; et < 16; ++et) {
      int er = et * 16 + l15;
      short8 bf = *(const short8*)((const char*)Wl +
                                   ((er * 512 + k0 * 2) ^ ((er & 7) << 4)));
      acc[et] = __builtin_amdgcn_mfma_f32_16x16x32_bf16(qa[kk], bf, acc[et], 0, 0, 0);
    }
  }
#pragma unroll
  for (int et = 0; et < 16; ++et) {
    int e = et * 16 + l15;
    float bv = K_b[e];
#pragma unroll
    for (int r = 0; r < 4; ++r)
      k[(m0 + hi * 4 + r) * 256 + e] = f2b(acc[et][r] + bv);
  }
}

// ---------------------------------------------------------------------------
// Fused attention, KEY-SPLIT: grid 512, each block = 64 q-rows x 512 keys
// (8 tiles). Per-CU staging volume unchanged vs r10, but 2 independent
// barrier groups per CU -> one block's compute fills the other's staging
// stall. launch_bounds(512,2): r21's (512,4) capped VGPR at 64 and spilled
// (WRITE 126 MB); (512,2) lets the compiler use ~124 VGPR (r10 level), which
// is <=128 so 2 blocks/CU still fit (LDS 75KB x2 = 150 < 160). Fixed-max
// softmax partials are additive: atomicAdd O into out (zeroed) + l into
// l_acc; finalize divides. Inner tile loop byte-identical to round-10.
#define SM_KT 0        // ushort Kt[64*256]   32768 B
#define SM_HT 32768    // ushort Ht[256*64]   32768 B
#define SM_PL 65536    // ushort Pl[8*16*32]   8192 B
#define SM_M2 73728    // uint   M2[2][128]    1024 B
#define SM_CM 74752    // float  Cm[64]         256 B
#define SM_SZ 75008

// P-buffer swizzle: XOR in bits>=4 keeps 16B blocks intact for ds_read_b128.
__device__ __forceinline__ int pswz(int row, int bytecol) {
  return (row * 64 + bytecol) ^ ((row & 7) << 4) ^ ((row >> 3) << 5);
}

__global__ __launch_bounds__(512, 2) void attn8(
    const ushort* __restrict__ Q, const ushort* __restrict__ Kb,
    const ushort* __restrict__ HT, const int* __restrict__ graph,
    float* __restrict__ out, float* __restrict__ l_acc) {
  __shared__ __align__(16) char smem[SM_SZ];
  ushort* Kt = (ushort*)(smem + SM_KT);
  ushort* Ht = (ushort*)(smem + SM_HT);
  ushort* Pl = (ushort*)(smem + SM_PL);
  uint* M2 = (uint*)(smem + SM_M2);
  float* Cm = (float*)(smem + SM_CM);

  const int tid = threadIdx.x;
  const int w = tid >> 6, lane = tid & 63, l15 = lane & 15, hi = lane >> 4;
  const int wg = w >> 1, half = w & 1;
  // XCD-aware remap: XCD x handles batches {2x, 2x+1}; 64 slots per XCD
  const int hw = blockIdx.x;
  const int slot = hw >> 3;                 // [0,64)
  const int b = (hw & 7) * 2 + (slot >> 5);
  const int rest = slot & 31;
  const int q0 = (rest >> 1) * 64;
  const int ks = rest & 1;                  // key half: [ks*512, ks*512+512)
  const int kt0 = ks * 8;                   // first key tile of this block
  const int qrow_a = q0 + wg * 16 + l15;
  const int qrow_cl = wg * 16 + hi * 4;  // local row base (+r)
  const int* grow_base =
      graph + (b * 1024 + q0 + w * 8) * 1024 + ks * 512 + lane;

  int greg[8];

  // ---- prologue: graph(tile kt0) + Q frags; ballot into M2[0] ----
#pragma unroll
  for (int j = 0; j < 8; ++j) greg[j] = grow_base[j * 1024];

  short8 qf[8];
#pragma unroll
  for (int kk = 0; kk < 8; ++kk)
    qf[kk] = *(const short8*)(Q + (b * 1024 + qrow_a) * 256 + kk * 32 + hi * 8);

#pragma unroll
  for (int j = 0; j < 8; ++j) {
    unsigned long long mm = __ballot(greg[j] != 0);
    if (lane == 0) {
      M2[(w * 8 + j) * 2] = (uint)mm;
      M2[(w * 8 + j) * 2 + 1] = (uint)(mm >> 32);
    }
  }

  float lR[4] = {0.f, 0.f, 0.f, 0.f};  // per-LANE partial row sums
  f32x4 o[16] = {};

  for (int t = 0; t < 8; ++t) {
    const uint* M2c = M2 + (t & 1) * 128;
    uint* M2n = M2 + ((t & 1) ^ 1) * 128;
    const int gk = (kt0 + t) * 64;  // global key offset of this tile

    __syncthreads();
#pragma unroll
    for (int i = 0; i < 4; ++i) {  // stage K tile [64][256]
      int c = i * 512 + tid;
      int krow = c >> 5, col0 = (c & 31) << 3;
      uint4 v = *(const uint4*)(Kb + (b * 1024 + gk + krow) * 256 + col0);
      *(uint4*)((char*)Kt + ((krow * 512 + col0 * 2) ^ ((krow & 7) << 4))) = v;
    }
#pragma unroll
    for (int i = 0; i < 4; ++i) {  // stage H^T tile [256][64]
      int c = i * 512 + tid;
      int drow = c >> 3, col0 = (c & 7) << 3;
      uint4 v = *(const uint4*)(HT + b * (256 * 1024) + drow * 1024 + gk + col0);
      *(uint4*)((char*)Ht + ((drow * 128 + col0 * 2) ^ ((drow & 7) << 4))) = v;
    }
    __syncthreads();

    // issue next tile's graph loads NOW; compute covers the HBM latency
    if (t < 7) {
#pragma unroll
      for (int j = 0; j < 8; ++j) greg[j] = grow_base[j * 1024 + (t + 1) * 64];
    }

    // S = q @ k^T : 16 rows x 32 keys (this wave's half)
    f32x4 s[2] = {};
    __builtin_amdgcn_s_setprio(1);
#pragma unroll
    for (int kk = 0; kk < 8; ++kk) {
#pragma unroll
      for (int nt = 0; nt < 2; ++nt) {
        int krow = half * 32 + nt * 16 + l15;
        short8 kf = *(const short8*)((const char*)Kt +
            ((krow * 512 + (kk * 32 + hi * 8) * 2) ^ ((krow & 7) << 4)));
        s[nt] = __builtin_amdgcn_mfma_f32_16x16x32_bf16(qf[kk], kf, s[nt], 0, 0, 0);
      }
    }
    __builtin_amdgcn_s_setprio(0);

    // scale, leaky, mask, exp — per-lane VALU only
    float p[2][4];
#pragma unroll
    for (int r = 0; r < 4; ++r) {
      uint mw = M2c[(qrow_cl + r) * 2 + half];
      float v0 = s[0][r] * 0.0625f; v0 = (v0 >= 0.f) ? v0 : 0.2f * v0;
      float v1 = s[1][r] * 0.0625f; v1 = (v1 >= 0.f) ? v1 : 0.2f * v1;
      float p0 = ((mw >> l15) & 1u) ? __expf(v0) : 0.f;
      float p1 = ((mw >> (16 + l15)) & 1u) ? __expf(v1) : 0.f;
      p[0][r] = p0; p[1][r] = p1;
      lR[r] += p0 + p1;
    }

    // P (C-layout) -> per-wave LDS -> A-frag layout
    ushort* Pw = Pl + w * 512;
#pragma unroll
    for (int nt = 0; nt < 2; ++nt)
#pragma unroll
      for (int r = 0; r < 4; ++r) {
        int row = hi * 4 + r, col = nt * 16 + l15;
        *(ushort*)((char*)Pw + pswz(row, col * 2)) = f2b(p[nt][r]);
      }
    __asm__ volatile("s_waitcnt lgkmcnt(0)" ::: "memory");
    short8 pa = *(const short8*)((const char*)Pw + pswz(l15, hi * 16));

    // O += P @ H (keys half*32 .. half*32+31)
    __builtin_amdgcn_s_setprio(1);
#pragma unroll
    for (int dt = 0; dt < 16; ++dt) {
      int dcol = dt * 16 + l15;
      short8 hf = *(const short8*)((const char*)Ht +
          ((dcol * 128 + (half * 32 + hi * 8) * 2) ^ ((dcol & 7) << 4)));
      o[dt] = __builtin_amdgcn_mfma_f32_16x16x32_bf16(pa, hf, o[dt], 0, 0, 0);
    }
    __builtin_amdgcn_s_setprio(0);

    // pack next tile's mask into the other M2 buffer
    if (t < 7) {
#pragma unroll
      for (int j = 0; j < 8; ++j) {
        unsigned long long mm = __ballot(greg[j] != 0);
        if (lane == 0) {
          M2n[(w * 8 + j) * 2] = (uint)mm;
          M2n[(w * 8 + j) * 2 + 1] = (uint)(mm >> 32);
        }
      }
    }
  }

  // ---- reduce row sums once (16-lane groups share a row set) ----
#pragma unroll
  for (int r = 0; r < 4; ++r) {
    lR[r] += __shfl_xor(lR[r], 1);
    lR[r] += __shfl_xor(lR[r], 2);
    lR[r] += __shfl_xor(lR[r], 4);
    lR[r] += __shfl_xor(lR[r], 8);
  }

  // ---- combine wave pairs; atomicAdd block partials to global ----
  __syncthreads();  // all tiles done; reuse smem[0,64K) = Kt+Ht as Ob
  float* Ob = (float*)smem;  // 4 pairs x [16][256] fp32 = 64 KB
  if (half == 1) {
#pragma unroll
    for (int dt = 0; dt < 16; ++dt)
#pragma unroll
      for (int r = 0; r < 4; ++r) {
        int row = hi * 4 + r;
        int byte = (row * 1024 + (dt * 16 + l15) * 4) ^ ((row & 15) << 6);
        *(float*)((char*)Ob + wg * 16384 + byte) = o[dt][r];
      }
    if (l15 == 0) {
#pragma unroll
      for (int r = 0; r < 4; ++r)
        Cm[wg * 16 + hi * 4 + r] = lR[r];
    }
  }
  __syncthreads();
  if (half == 0) {
#pragma unroll
    for (int r = 0; r < 4; ++r) {
      int rowl = hi * 4 + r;
      float lpart = lR[r] + Cm[wg * 16 + rowl];
      int orow = b * 1024 + q0 + wg * 16 + rowl;
      if (l15 == 0) atomicAdd(&l_acc[orow], lpart);
#pragma unroll
      for (int dt = 0; dt < 16; ++dt) {
        int byte = (rowl * 1024 + (dt * 16 + l15) * 4) ^ ((rowl & 15) << 6);
        float ob = *(const float*)((const char*)Ob + wg * 16384 + byte);
        atomicAdd(&out[orow * 256 + dt * 16 + l15], o[dt][r] + ob);
      }
    }
  }
}

// ---------------------------------------------------------------------------
// out = relu(out) / l_acc  (relu(o/l) == relu(o)/l since l > 0)
__global__ __launch_bounds__(256) void finalize(float* __restrict__ out,
                                                const float* __restrict__ l_acc) {
  const long i4 = (long)blockIdx.x * blockDim.x + threadIdx.x;
  const long n4 = (long)MTOT * DD / 4;
  const long stride = (long)gridDim.x * blockDim.x;
  for (long i = i4; i < n4; i += stride) {
    float4 v = ((const float4*)out)[i];
    float inv = 1.f / l_acc[(i * 4) >> 8];
    v.x = fmaxf(v.x, 0.f) * inv;
    v.y = fmaxf(v.y, 0.f) * inv;
    v.z = fmaxf(v.z, 0.f) * inv;
    v.w = fmaxf(v.w, 0.f) * inv;
    ((float4*)out)[i] = v;
  }
}

// ---------------------------------------------------------------------------
extern "C" void kernel_launch(void* const* d_in, const int* in_sizes, int n_in,
                              void* d_out, int out_size, void* d_ws,
                              size_t ws_size, hipStream_t stream) {
  const float* feature = (const float*)d_in[0];
  const int* graph = (const int*)d_in[1];
  const float* W_w = (const float*)d_in[2];
  const float* W_b = (const float*)d_in[3];
  const float* Q_w = (const float*)d_in[4];
  const float* Q_b = (const float*)d_in[5];
  const float* K_w = (const float*)d_in[6];
  const float* K_b = (const float*)d_in[7];
  float* out = (float*)d_out;

  ushort* hT = (ushort*)d_ws;         // [B,D,N] bf16   8 MB
  ushort* q = hT + MTOT * DD;         // [B,N,D] bf16   8 MB
  ushort* k = q + MTOT * DD;          // [B,N,D] bf16   8 MB
  float* l_acc = (float*)(k + MTOT * DD);  // [B,N] fp32  64 KB

  hipMemsetAsync(out, 0, (size_t)MTOT * DD * sizeof(float), stream);
  hipMemsetAsync(l_acc, 0, (size_t)MTOT * sizeof(float), stream);
  gemm_fused<<<256, 256, 0, stream>>>(feature, W_w, W_b, Q_w, Q_b, K_w, K_b,
                                      hT, q, k);
  attn8<<<512, 512, 0, stream>>>(q, k, hT, graph, out, l_acc);
  finalize<<<1024, 256, 0, stream>>>(out, l_acc);
}

// Round 23
// 93.549 us; speedup vs baseline: 2.6535x; 1.4214x over previous
//
#include <hip/hip_runtime.h>
#include <hip/hip_bf16.h>
#include <stdint.h>

#define DD 256
#define NB 16
#define NN 1024
#define MTOT (NB * NN)  // 16384

typedef __attribute__((ext_vector_type(8))) short short8;
typedef __attribute__((ext_vector_type(4))) float f32x4;

__device__ __forceinline__ ushort f2b(float f) {
  uint32_t u = __float_as_uint(f);
  return (ushort)((u + 0x7fffu + ((u >> 16) & 1u)) >> 16);
}

// Stage a 256x256 fp32 weight matrix into LDS as bf16, XOR-swizzled rows.
__device__ __forceinline__ void stage_weights(const float* __restrict__ W,
                                              ushort* Wl, int tid) {
  for (int i = 0; i < 64; ++i) {
    int idx4 = i * 256 + tid;
    int row = idx4 >> 6;
    int col0 = (idx4 & 63) << 2;
    float4 v = ((const float4*)W)[idx4];
    ushort4 b4;
    b4.x = f2b(v.x); b4.y = f2b(v.y); b4.z = f2b(v.z); b4.w = f2b(v.w);
    int byte = (row * 512 + col0 * 2) ^ ((row & 7) << 4);
    *(ushort4*)((char*)Wl + byte) = b4;
  }
}

// ---------------------------------------------------------------------------
// Fused h/q/k GEMM (round-13 winner, unchanged). Each block owns 64 rows.
__global__ __launch_bounds__(256, 1) void gemm_fused(
    const float* __restrict__ feature, const float* __restrict__ W_w,
    const float* __restrict__ W_b, const float* __restrict__ Q_w,
    const float* __restrict__ Q_b, const float* __restrict__ K_w,
    const float* __restrict__ K_b, ushort* __restrict__ hT,
    ushort* __restrict__ q, ushort* __restrict__ k) {
  __shared__ ushort Wl[256 * 256];  // 128 KB; doubles as Tl transpose buffer
  const int tid = threadIdx.x;
  const int w = tid >> 6, lane = tid & 63, l15 = lane & 15, hi = lane >> 4;
  const int m0 = blockIdx.x * 64 + w * 16;
  const int arow = m0 + l15;

  // ---- h = feature @ W_w^T + W_b ----
  stage_weights(W_w, Wl, tid);
  __syncthreads();

  f32x4 acc[16] = {};
#pragma unroll
  for (int kk = 0; kk < 8; ++kk) {
    const int k0 = kk * 32 + hi * 8;
    const float4* ap = (const float4*)(feature + arow * 256 + k0);
    float4 x = ap[0], y = ap[1];
    short8 a;
    a[0] = (short)f2b(x.x); a[1] = (short)f2b(x.y);
    a[2] = (short)f2b(x.z); a[3] = (short)f2b(x.w);
    a[4] = (short)f2b(y.x); a[5] = (short)f2b(y.y);
    a[6] = (short)f2b(y.z); a[7] = (short)f2b(y.w);
#pragma unroll
    for (int et = 0; et < 16; ++et) {
      int er = et * 16 + l15;
      short8 bf = *(const short8*)((const char*)Wl +
                                   ((er * 512 + k0 * 2) ^ ((er & 7) << 4)));
      acc[et] = __builtin_amdgcn_mfma_f32_16x16x32_bf16(a, bf, acc[et], 0, 0, 0);
    }
  }

  ushort hvals[16][4];
#pragma unroll
  for (int et = 0; et < 16; ++et) {
    float bv = W_b[et * 16 + l15];
#pragma unroll
    for (int r = 0; r < 4; ++r) hvals[et][r] = f2b(acc[et][r] + bv);
  }

  // ---- transpose h into Tl(=Wl) [256][64] ----
  __syncthreads();  // all waves done reading Wl
  ushort* Tl = Wl;
  {
    const int mloc = w * 16 + hi * 4;
#pragma unroll
    for (int et = 0; et < 16; ++et)
#pragma unroll
      for (int r = 0; r < 4; ++r)
        Tl[(et * 16 + l15) * 64 + mloc + r] = hvals[et][r];
  }
  __syncthreads();

  // ---- (a) h A-frags back to registers; (b) hT to global ----
  short8 qa[8];
#pragma unroll
  for (int kk = 0; kk < 8; ++kk) {
    const int k0 = kk * 32 + hi * 8;
#pragma unroll
    for (int j = 0; j < 8; ++j)
      qa[kk][j] = (short)Tl[(k0 + j) * 64 + w * 16 + l15];
  }
  {
    const int bidx = blockIdx.x >> 4;
    const int n0 = (blockIdx.x & 15) * 64;
    ushort* dst = hT + bidx * (256 * 1024) + tid * 1024 + n0;
    const uint4* src = (const uint4*)(Tl + tid * 64);
#pragma unroll
    for (int j = 0; j < 8; ++j) ((uint4*)dst)[j] = src[j];
  }
  __syncthreads();  // Tl reads done before Q_w staging overwrites

  // ---- q = h @ Q_w^T + Q_b ----
  stage_weights(Q_w, Wl, tid);
  __syncthreads();
#pragma unroll
  for (int et = 0; et < 16; ++et) acc[et] = (f32x4){0.f, 0.f, 0.f, 0.f};
#pragma unroll
  for (int kk = 0; kk < 8; ++kk) {
    const int k0 = kk * 32 + hi * 8;
#pragma unroll
    for (int et = 0; et < 16; ++et) {
      int er = et * 16 + l15;
      short8 bf = *(const short8*)((const char*)Wl +
                                   ((er * 512 + k0 * 2) ^ ((er & 7) << 4)));
      acc[et] = __builtin_amdgcn_mfma_f32_16x16x32_bf16(qa[kk], bf, acc[et], 0, 0, 0);
    }
  }
#pragma unroll
  for (int et = 0; et < 16; ++et) {
    int e = et * 16 + l15;
    float bv = Q_b[e];
#pragma unroll
    for (int r = 0; r < 4; ++r)
      q[(m0 + hi * 4 + r) * 256 + e] = f2b(acc[et][r] + bv);
  }
  __syncthreads();  // q-compute reads of Wl done before K_w staging

  // ---- k = h @ K_w^T + K_b ----
  stage_weights(K_w, Wl, tid);
  __syncthreads();
#pragma unroll
  for (int et = 0; et < 16; ++et) acc[et] = (f32x4){0.f, 0.f, 0.f, 0.f};
#pragma unroll
  for (int kk = 0; kk < 8; ++kk) {
    const int k0 = kk * 32 + hi * 8;
#pragma unroll
    for (int et = 0; et < 16; ++et) {
      int er = et * 16 + l15;
      short8 bf = *(const short8*)((const char*)Wl +
                                   ((er * 512 + k0 * 2) ^ ((er & 7) << 4)));
      acc[et] = __builtin_amdgcn_mfma_f32_16x16x32_bf16(qa[kk], bf, acc[et], 0, 0, 0);
    }
  }
#pragma unroll
  for (int et = 0; et < 16; ++et) {
    int e = et * 16 + l15;
    float bv = K_b[e];
#pragma unroll
    for (int r = 0; r < 4; ++r)
      k[(m0 + hi * 4 + r) * 256 + e] = f2b(acc[et][r] + bv);
  }
}

// ---------------------------------------------------------------------------
// Fused attention (round-10 structure, the verified best): 8 waves, wave-pair
// key split, fixed-max softmax, in-loop graph->bitmask pack (double-buffered
// M2), standard pair-combine epilogue.
#define SM_KT 0        // ushort Kt[64*256]   32768 B
#define SM_HT 32768    // ushort Ht[256*64]   32768 B
#define SM_PL 65536    // ushort Pl[8*16*32]   8192 B
#define SM_M2 73728    // uint   M2[2][128]    1024 B
#define SM_CM 74752    // float  Cm[64]         256 B
#define SM_SZ 75008

// P-buffer swizzle: XOR in bits>=4 keeps 16B blocks intact for ds_read_b128.
__device__ __forceinline__ int pswz(int row, int bytecol) {
  return (row * 64 + bytecol) ^ ((row & 7) << 4) ^ ((row >> 3) << 5);
}

__global__ __launch_bounds__(512, 2) void attn8(
    const ushort* __restrict__ Q, const ushort* __restrict__ Kb,
    const ushort* __restrict__ HT, const int* __restrict__ graph,
    float* __restrict__ out) {
  __shared__ __align__(16) char smem[SM_SZ];
  ushort* Kt = (ushort*)(smem + SM_KT);
  ushort* Ht = (ushort*)(smem + SM_HT);
  ushort* Pl = (ushort*)(smem + SM_PL);
  uint* M2 = (uint*)(smem + SM_M2);
  float* Cm = (float*)(smem + SM_CM);

  const int tid = threadIdx.x;
  const int w = tid >> 6, lane = tid & 63, l15 = lane & 15, hi = lane >> 4;
  const int wg = w >> 1, half = w & 1;
  // XCD-aware remap: XCD x handles batches {2x, 2x+1}
  const int hw = blockIdx.x;
  const int slot = hw >> 3;
  const int b = (hw & 7) * 2 + (slot >> 4);
  const int q0 = (slot & 15) * 64;
  const int qrow_a = q0 + wg * 16 + l15;
  const int qrow_cl = wg * 16 + hi * 4;  // local row base (+r)
  const int* grow_base = graph + (b * 1024 + q0 + w * 8) * 1024 + lane;

  int greg[8];

  // ---- prologue: graph(0) + Q frags; ballot into M2[0] ----
#pragma unroll
  for (int j = 0; j < 8; ++j) greg[j] = grow_base[j * 1024];

  short8 qf[8];
#pragma unroll
  for (int kk = 0; kk < 8; ++kk)
    qf[kk] = *(const short8*)(Q + (b * 1024 + qrow_a) * 256 + kk * 32 + hi * 8);

#pragma unroll
  for (int j = 0; j < 8; ++j) {
    unsigned long long mm = __ballot(greg[j] != 0);
    if (lane == 0) {
      M2[(w * 8 + j) * 2] = (uint)mm;
      M2[(w * 8 + j) * 2 + 1] = (uint)(mm >> 32);
    }
  }

  float lR[4] = {0.f, 0.f, 0.f, 0.f};  // per-LANE partial row sums
  f32x4 o[16] = {};

  for (int t = 0; t < 16; ++t) {
    const uint* M2c = M2 + (t & 1) * 128;
    uint* M2n = M2 + ((t & 1) ^ 1) * 128;

    __syncthreads();
#pragma unroll
    for (int i = 0; i < 4; ++i) {  // stage K tile [64][256]
      int c = i * 512 + tid;
      int krow = c >> 5, col0 = (c & 31) << 3;
      uint4 v = *(const uint4*)(Kb + (b * 1024 + t * 64 + krow) * 256 + col0);
      *(uint4*)((char*)Kt + ((krow * 512 + col0 * 2) ^ ((krow & 7) << 4))) = v;
    }
#pragma unroll
    for (int i = 0; i < 4; ++i) {  // stage H^T tile [256][64]
      int c = i * 512 + tid;
      int drow = c >> 3, col0 = (c & 7) << 3;
      uint4 v = *(const uint4*)(HT + b * (256 * 1024) + drow * 1024 + t * 64 + col0);
      *(uint4*)((char*)Ht + ((drow * 128 + col0 * 2) ^ ((drow & 7) << 4))) = v;
    }
    __syncthreads();

    // issue next tile's graph loads NOW; compute covers the HBM latency
    if (t < 15) {
#pragma unroll
      for (int j = 0; j < 8; ++j) greg[j] = grow_base[j * 1024 + (t + 1) * 64];
    }

    // S = q @ k^T : 16 rows x 32 keys (this wave's half)
    f32x4 s[2] = {};
    __builtin_amdgcn_s_setprio(1);
#pragma unroll
    for (int kk = 0; kk < 8; ++kk) {
#pragma unroll
      for (int nt = 0; nt < 2; ++nt) {
        int krow = half * 32 + nt * 16 + l15;
        short8 kf = *(const short8*)((const char*)Kt +
            ((krow * 512 + (kk * 32 + hi * 8) * 2) ^ ((krow & 7) << 4)));
        s[nt] = __builtin_amdgcn_mfma_f32_16x16x32_bf16(qf[kk], kf, s[nt], 0, 0, 0);
      }
    }
    __builtin_amdgcn_s_setprio(0);

    // scale, leaky, mask, exp — per-lane VALU only
    float p[2][4];
#pragma unroll
    for (int r = 0; r < 4; ++r) {
      uint mw = M2c[(qrow_cl + r) * 2 + half];
      float v0 = s[0][r] * 0.0625f; v0 = (v0 >= 0.f) ? v0 : 0.2f * v0;
      float v1 = s[1][r] * 0.0625f; v1 = (v1 >= 0.f) ? v1 : 0.2f * v1;
      float p0 = ((mw >> l15) & 1u) ? __expf(v0) : 0.f;
      float p1 = ((mw >> (16 + l15)) & 1u) ? __expf(v1) : 0.f;
      p[0][r] = p0; p[1][r] = p1;
      lR[r] += p0 + p1;
    }

    // P (C-layout) -> per-wave LDS -> A-frag layout
    ushort* Pw = Pl + w * 512;
#pragma unroll
    for (int nt = 0; nt < 2; ++nt)
#pragma unroll
      for (int r = 0; r < 4; ++r) {
        int row = hi * 4 + r, col = nt * 16 + l15;
        *(ushort*)((char*)Pw + pswz(row, col * 2)) = f2b(p[nt][r]);
      }
    __asm__ volatile("s_waitcnt lgkmcnt(0)" ::: "memory");
    short8 pa = *(const short8*)((const char*)Pw + pswz(l15, hi * 16));

    // O += P @ H (keys half*32 .. half*32+31)
    __builtin_amdgcn_s_setprio(1);
#pragma unroll
    for (int dt = 0; dt < 16; ++dt) {
      int dcol = dt * 16 + l15;
      short8 hf = *(const short8*)((const char*)Ht +
          ((dcol * 128 + (half * 32 + hi * 8) * 2) ^ ((dcol & 7) << 4)));
      o[dt] = __builtin_amdgcn_mfma_f32_16x16x32_bf16(pa, hf, o[dt], 0, 0, 0);
    }
    __builtin_amdgcn_s_setprio(0);

    // pack next tile's mask into the other M2 buffer (race-free: readers of
    // M2n only run after the loop-top barrier)
    if (t < 15) {
#pragma unroll
      for (int j = 0; j < 8; ++j) {
        unsigned long long mm = __ballot(greg[j] != 0);
        if (lane == 0) {
          M2n[(w * 8 + j) * 2] = (uint)mm;
          M2n[(w * 8 + j) * 2 + 1] = (uint)(mm >> 32);
        }
      }
    }
  }

  // ---- reduce row sums once (16-lane groups share a row set) ----
#pragma unroll
  for (int r = 0; r < 4; ++r) {
    lR[r] += __shfl_xor(lR[r], 1);
    lR[r] += __shfl_xor(lR[r], 2);
    lR[r] += __shfl_xor(lR[r], 4);
    lR[r] += __shfl_xor(lR[r], 8);
  }

  // ---- combine wave pairs, epilogue ----
  __syncthreads();  // all tiles done; reuse smem[0,64K) = Kt+Ht as Ob
  float* Ob = (float*)smem;  // 4 pairs x [16][256] fp32 = 64 KB
  if (half == 1) {
#pragma unroll
    for (int dt = 0; dt < 16; ++dt)
#pragma unroll
      for (int r = 0; r < 4; ++r) {
        int row = hi * 4 + r;
        int byte = (row * 1024 + (dt * 16 + l15) * 4) ^ ((row & 15) << 6);
        *(float*)((char*)Ob + wg * 16384 + byte) = o[dt][r];
      }
    if (l15 == 0) {
#pragma unroll
      for (int r = 0; r < 4; ++r)
        Cm[wg * 16 + hi * 4 + r] = lR[r];
    }
  }
  __syncthreads();
  if (half == 0) {
#pragma unroll
    for (int r = 0; r < 4; ++r) {
      int rowl = hi * 4 + r;
      float inv = 1.f / (lR[r] + Cm[wg * 16 + rowl]);
      int orow = b * 1024 + q0 + wg * 16 + rowl;
#pragma unroll
      for (int dt = 0; dt < 16; ++dt) {
        int byte = (rowl * 1024 + (dt * 16 + l15) * 4) ^ ((rowl & 15) << 6);
        float ob = *(const float*)((const char*)Ob + wg * 16384 + byte);
        float v = (o[dt][r] + ob) * inv;
        out[orow * 256 + dt * 16 + l15] = fmaxf(v, 0.f);
      }
    }
  }
}

// ---------------------------------------------------------------------------
extern "C" void kernel_launch(void* const* d_in, const int* in_sizes, int n_in,
                              void* d_out, int out_size, void* d_ws,
                              size_t ws_size, hipStream_t stream) {
  const float* feature = (const float*)d_in[0];
  const int* graph = (const int*)d_in[1];
  const float* W_w = (const float*)d_in[2];
  const float* W_b = (const float*)d_in[3];
  const float* Q_w = (const float*)d_in[4];
  const float* Q_b = (const float*)d_in[5];
  const float* K_w = (const float*)d_in[6];
  const float* K_b = (const float*)d_in[7];
  float* out = (float*)d_out;

  ushort* hT = (ushort*)d_ws;         // [B,D,N] bf16   8 MB
  ushort* q = hT + MTOT * DD;         // [B,N,D] bf16   8 MB
  ushort* k = q + MTOT * DD;          // [B,N,D] bf16   8 MB

  gemm_fused<<<256, 256, 0, stream>>>(feature, W_w, W_b, Q_w, Q_b, K_w, K_b,
                                      hT, q, k);
  attn8<<<256, 512, 0, stream>>>(q, k, hT, graph, out);
}

// Round 24
// 91.144 us; speedup vs baseline: 2.7235x; 1.0264x over previous
//
#include <hip/hip_runtime.h>
#include <hip/hip_bf16.h>
#include <stdint.h>

#define DD 256
#define NB 16
#define NN 1024
#define MTOT (NB * NN)  // 16384

typedef __attribute__((ext_vector_type(8))) short short8;
typedef __attribute__((ext_vector_type(4))) float f32x4;

__device__ __forceinline__ ushort f2b(float f) {
  uint32_t u = __float_as_uint(f);
  return (ushort)((u + 0x7fffu + ((u >> 16) & 1u)) >> 16);
}

// Stage a 256x256 fp32 weight matrix into LDS as bf16, XOR-swizzled rows.
__device__ __forceinline__ void stage_weights(const float* __restrict__ W,
                                              ushort* Wl, int tid) {
  for (int i = 0; i < 64; ++i) {
    int idx4 = i * 256 + tid;
    int row = idx4 >> 6;
    int col0 = (idx4 & 63) << 2;
    float4 v = ((const float4*)W)[idx4];
    ushort4 b4;
    b4.x = f2b(v.x); b4.y = f2b(v.y); b4.z = f2b(v.z); b4.w = f2b(v.w);
    int byte = (row * 512 + col0 * 2) ^ ((row & 7) << 4);
    *(ushort4*)((char*)Wl + byte) = b4;
  }
}

// ---------------------------------------------------------------------------
// Fused h/q/k GEMM (round-13 winner, unchanged). Each block owns 64 rows.
__global__ __launch_bounds__(256, 1) void gemm_fused(
    const float* __restrict__ feature, const float* __restrict__ W_w,
    const float* __restrict__ W_b, const float* __restrict__ Q_w,
    const float* __restrict__ Q_b, const float* __restrict__ K_w,
    const float* __restrict__ K_b, ushort* __restrict__ hT,
    ushort* __restrict__ q, ushort* __restrict__ k) {
  __shared__ ushort Wl[256 * 256];  // 128 KB; doubles as Tl transpose buffer
  const int tid = threadIdx.x;
  const int w = tid >> 6, lane = tid & 63, l15 = lane & 15, hi = lane >> 4;
  const int m0 = blockIdx.x * 64 + w * 16;
  const int arow = m0 + l15;

  // ---- h = feature @ W_w^T + W_b ----
  stage_weights(W_w, Wl, tid);
  __syncthreads();

  f32x4 acc[16] = {};
#pragma unroll
  for (int kk = 0; kk < 8; ++kk) {
    const int k0 = kk * 32 + hi * 8;
    const float4* ap = (const float4*)(feature + arow * 256 + k0);
    float4 x = ap[0], y = ap[1];
    short8 a;
    a[0] = (short)f2b(x.x); a[1] = (short)f2b(x.y);
    a[2] = (short)f2b(x.z); a[3] = (short)f2b(x.w);
    a[4] = (short)f2b(y.x); a[5] = (short)f2b(y.y);
    a[6] = (short)f2b(y.z); a[7] = (short)f2b(y.w);
#pragma unroll
    for (int et = 0; et < 16; ++et) {
      int er = et * 16 + l15;
      short8 bf = *(const short8*)((const char*)Wl +
                                   ((er * 512 + k0 * 2) ^ ((er & 7) << 4)));
      acc[et] = __builtin_amdgcn_mfma_f32_16x16x32_bf16(a, bf, acc[et], 0, 0, 0);
    }
  }

  ushort hvals[16][4];
#pragma unroll
  for (int et = 0; et < 16; ++et) {
    float bv = W_b[et * 16 + l15];
#pragma unroll
    for (int r = 0; r < 4; ++r) hvals[et][r] = f2b(acc[et][r] + bv);
  }

  // ---- transpose h into Tl(=Wl) [256][64] ----
  __syncthreads();  // all waves done reading Wl
  ushort* Tl = Wl;
  {
    const int mloc = w * 16 + hi * 4;
#pragma unroll
    for (int et = 0; et < 16; ++et)
#pragma unroll
      for (int r = 0; r < 4; ++r)
        Tl[(et * 16 + l15) * 64 + mloc + r] = hvals[et][r];
  }
  __syncthreads();

  // ---- (a) h A-frags back to registers; (b) hT to global ----
  short8 qa[8];
#pragma unroll
  for (int kk = 0; kk < 8; ++kk) {
    const int k0 = kk * 32 + hi * 8;
#pragma unroll
    for (int j = 0; j < 8; ++j)
      qa[kk][j] = (short)Tl[(k0 + j) * 64 + w * 16 + l15];
  }
  {
    const int bidx = blockIdx.x >> 4;
    const int n0 = (blockIdx.x & 15) * 64;
    ushort* dst = hT + bidx * (256 * 1024) + tid * 1024 + n0;
    const uint4* src = (const uint4*)(Tl + tid * 64);
#pragma unroll
    for (int j = 0; j < 8; ++j) ((uint4*)dst)[j] = src[j];
  }
  __syncthreads();  // Tl reads done before Q_w staging overwrites

  // ---- q = h @ Q_w^T + Q_b ----
  stage_weights(Q_w, Wl, tid);
  __syncthreads();
#pragma unroll
  for (int et = 0; et < 16; ++et) acc[et] = (f32x4){0.f, 0.f, 0.f, 0.f};
#pragma unroll
  for (int kk = 0; kk < 8; ++kk) {
    const int k0 = kk * 32 + hi * 8;
#pragma unroll
    for (int et = 0; et < 16; ++et) {
      int er = et * 16 + l15;
      short8 bf = *(const short8*)((const char*)Wl +
                                   ((er * 512 + k0 * 2) ^ ((er & 7) << 4)));
      acc[et] = __builtin_amdgcn_mfma_f32_16x16x32_bf16(qa[kk], bf, acc[et], 0, 0, 0);
    }
  }
#pragma unroll
  for (int et = 0; et < 16; ++et) {
    int e = et * 16 + l15;
    float bv = Q_b[e];
#pragma unroll
    for (int r = 0; r < 4; ++r)
      q[(m0 + hi * 4 + r) * 256 + e] = f2b(acc[et][r] + bv);
  }
  __syncthreads();  // q-compute reads of Wl done before K_w staging

  // ---- k = h @ K_w^T + K_b ----
  stage_weights(K_w, Wl, tid);
  __syncthreads();
#pragma unroll
  for (int et = 0; et < 16; ++et) acc[et] = (f32x4){0.f, 0.f, 0.f, 0.f};
#pragma unroll
  for (int kk = 0; kk < 8; ++kk) {
    const int k0 = kk * 32 + hi * 8;
#pragma unroll
    for (int et = 0; et < 16; ++et) {
      int er = et * 16 + l15;
      short8 bf = *(const short8*)((const char*)Wl +
                                   ((er * 512 + k0 * 2) ^ ((er & 7) << 4)));
      acc[et] = __builtin_amdgcn_mfma_f32_16x16x32_bf16(qa[kk], bf, acc[et], 0, 0, 0);
    }
  }
#pragma unroll
  for (int et = 0; et < 16; ++et) {
    int e = et * 16 + l15;
    float bv = K_b[e];
#pragma unroll
    for (int r = 0; r < 4; ++r)
      k[(m0 + hi * 4 + r) * 256 + e] = f2b(acc[et][r] + bv);
  }
}

// ---------------------------------------------------------------------------
// Fused attention: r10 inner compute with DOUBLE-BUFFERED staging and ONE
// barrier per tile. Race proof: STAGE(t+1) writes buf[(t+1)%2], last read by
// COMPUTE(t-1); the end-of-iter-(t-1) barrier orders all of COMPUTE(t-1)
// before any STAGE(t+1). COMPUTE(t) reads the buffer staged in iter t-1,
// ordered by the same barrier. M2 parity pairs likewise span one barrier.
#define SM_KT0 0       // ushort [64*256]  32768 B
#define SM_KT1 32768   // ushort [64*256]  32768 B
#define SM_HT0 65536   // ushort [256*64]  32768 B
#define SM_HT1 98304   // ushort [256*64]  32768 B
#define SM_PL 131072   // ushort Pl[8*16*32]  8192 B
#define SM_M2 139264   // uint   M2[2][128]   1024 B
#define SM_CM 140288   // float  Cm[64]        256 B
#define SM_SZ 140544

// P-buffer swizzle: XOR in bits>=4 keeps 16B blocks intact for ds_read_b128.
__device__ __forceinline__ int pswz(int row, int bytecol) {
  return (row * 64 + bytecol) ^ ((row & 7) << 4) ^ ((row >> 3) << 5);
}

__global__ __launch_bounds__(512, 2) void attn8(
    const ushort* __restrict__ Q, const ushort* __restrict__ Kb,
    const ushort* __restrict__ HT, const int* __restrict__ graph,
    float* __restrict__ out) {
  __shared__ __align__(16) char smem[SM_SZ];
  ushort* Pl = (ushort*)(smem + SM_PL);
  uint* M2 = (uint*)(smem + SM_M2);
  float* Cm = (float*)(smem + SM_CM);

  const int tid = threadIdx.x;
  const int w = tid >> 6, lane = tid & 63, l15 = lane & 15, hi = lane >> 4;
  const int wg = w >> 1, half = w & 1;
  // XCD-aware remap: XCD x handles batches {2x, 2x+1}
  const int hw = blockIdx.x;
  const int slot = hw >> 3;
  const int b = (hw & 7) * 2 + (slot >> 4);
  const int q0 = (slot & 15) * 64;
  const int qrow_a = q0 + wg * 16 + l15;
  const int qrow_cl = wg * 16 + hi * 4;  // local row base (+r)
  const int* grow_base = graph + (b * 1024 + q0 + w * 8) * 1024 + lane;

  int greg[8];

  // stage tile tt's K/H^T into buffer pair bb (0 or 1); r10-identical layout
#define STAGE_TILE(tt, bb)                                                    \
  {                                                                           \
    ushort* Kd = (ushort*)(smem + ((bb) ? SM_KT1 : SM_KT0));                  \
    ushort* Hd = (ushort*)(smem + ((bb) ? SM_HT1 : SM_HT0));                  \
    _Pragma("unroll") for (int i = 0; i < 4; ++i) {                           \
      int c = i * 512 + tid;                                                  \
      int krow = c >> 5, col0 = (c & 31) << 3;                                \
      uint4 v =                                                               \
          *(const uint4*)(Kb + (b * 1024 + (tt) * 64 + krow) * 256 + col0);   \
      *(uint4*)((char*)Kd + ((krow * 512 + col0 * 2) ^ ((krow & 7) << 4))) =  \
          v;                                                                  \
    }                                                                         \
    _Pragma("unroll") for (int i = 0; i < 4; ++i) {                           \
      int c = i * 512 + tid;                                                  \
      int drow = c >> 3, col0 = (c & 7) << 3;                                 \
      uint4 v = *(const uint4*)(HT + b * (256 * 1024) + drow * 1024 +         \
                                (tt) * 64 + col0);                            \
      *(uint4*)((char*)Hd + ((drow * 128 + col0 * 2) ^ ((drow & 7) << 4))) =  \
          v;                                                                  \
    }                                                                         \
  }

  // ---- prologue: stage tile 0 into buf0; graph(0) ballot into M2[0] ----
#pragma unroll
  for (int j = 0; j < 8; ++j) greg[j] = grow_base[j * 1024];

  STAGE_TILE(0, 0);

  short8 qf[8];
#pragma unroll
  for (int kk = 0; kk < 8; ++kk)
    qf[kk] = *(const short8*)(Q + (b * 1024 + qrow_a) * 256 + kk * 32 + hi * 8);

#pragma unroll
  for (int j = 0; j < 8; ++j) {
    unsigned long long mm = __ballot(greg[j] != 0);
    if (lane == 0) {
      M2[(w * 8 + j) * 2] = (uint)mm;
      M2[(w * 8 + j) * 2 + 1] = (uint)(mm >> 32);
    }
  }

  float lR[4] = {0.f, 0.f, 0.f, 0.f};  // per-LANE partial row sums
  f32x4 o[16] = {};

  __syncthreads();  // tile 0 staged

  for (int t = 0; t < 16; ++t) {
    const int cur = t & 1;
    const ushort* Kt = (const ushort*)(smem + (cur ? SM_KT1 : SM_KT0));
    const ushort* Ht = (const ushort*)(smem + (cur ? SM_HT1 : SM_HT0));
    const uint* M2c = M2 + cur * 128;
    uint* M2n = M2 + (cur ^ 1) * 128;

    // issue next tile's graph loads NOW; compute covers the HBM latency
    if (t < 15) {
#pragma unroll
      for (int j = 0; j < 8; ++j) greg[j] = grow_base[j * 1024 + (t + 1) * 64];
    }

    // S = q @ k^T : 16 rows x 32 keys (this wave's half)
    f32x4 s[2] = {};
    __builtin_amdgcn_s_setprio(1);
#pragma unroll
    for (int kk = 0; kk < 8; ++kk) {
#pragma unroll
      for (int nt = 0; nt < 2; ++nt) {
        int krow = half * 32 + nt * 16 + l15;
        short8 kf = *(const short8*)((const char*)Kt +
            ((krow * 512 + (kk * 32 + hi * 8) * 2) ^ ((krow & 7) << 4)));
        s[nt] = __builtin_amdgcn_mfma_f32_16x16x32_bf16(qf[kk], kf, s[nt], 0, 0, 0);
      }
    }
    __builtin_amdgcn_s_setprio(0);

    // scale, leaky, mask, exp — per-lane VALU only
    float p[2][4];
#pragma unroll
    for (int r = 0; r < 4; ++r) {
      uint mw = M2c[(qrow_cl + r) * 2 + half];
      float v0 = s[0][r] * 0.0625f; v0 = (v0 >= 0.f) ? v0 : 0.2f * v0;
      float v1 = s[1][r] * 0.0625f; v1 = (v1 >= 0.f) ? v1 : 0.2f * v1;
      float p0 = ((mw >> l15) & 1u) ? __expf(v0) : 0.f;
      float p1 = ((mw >> (16 + l15)) & 1u) ? __expf(v1) : 0.f;
      p[0][r] = p0; p[1][r] = p1;
      lR[r] += p0 + p1;
    }

    // P (C-layout) -> per-wave LDS -> A-frag layout
    ushort* Pw = Pl + w * 512;
#pragma unroll
    for (int nt = 0; nt < 2; ++nt)
#pragma unroll
      for (int r = 0; r < 4; ++r) {
        int row = hi * 4 + r, col = nt * 16 + l15;
        *(ushort*)((char*)Pw + pswz(row, col * 2)) = f2b(p[nt][r]);
      }
    __asm__ volatile("s_waitcnt lgkmcnt(0)" ::: "memory");
    short8 pa = *(const short8*)((const char*)Pw + pswz(l15, hi * 16));

    // O += P @ H (keys half*32 .. half*32+31)
    __builtin_amdgcn_s_setprio(1);
#pragma unroll
    for (int dt = 0; dt < 16; ++dt) {
      int dcol = dt * 16 + l15;
      short8 hf = *(const short8*)((const char*)Ht +
          ((dcol * 128 + (half * 32 + hi * 8) * 2) ^ ((dcol & 7) << 4)));
      o[dt] = __builtin_amdgcn_mfma_f32_16x16x32_bf16(pa, hf, o[dt], 0, 0, 0);
    }
    __builtin_amdgcn_s_setprio(0);

    if (t < 15) {
      // ballot next tile's mask into the other parity
#pragma unroll
      for (int j = 0; j < 8; ++j) {
        unsigned long long mm = __ballot(greg[j] != 0);
        if (lane == 0) {
          M2n[(w * 8 + j) * 2] = (uint)mm;
          M2n[(w * 8 + j) * 2 + 1] = (uint)(mm >> 32);
        }
      }
      // stage next tile into the other buffer (early waves overlap slow
      // waves' compute; write target protected by the iter-(t-1) barrier)
      STAGE_TILE(t + 1, cur ^ 1);
    }

    __syncthreads();  // single barrier per tile
  }

  // ---- reduce row sums once (16-lane groups share a row set) ----
#pragma unroll
  for (int r = 0; r < 4; ++r) {
    lR[r] += __shfl_xor(lR[r], 1);
    lR[r] += __shfl_xor(lR[r], 2);
    lR[r] += __shfl_xor(lR[r], 4);
    lR[r] += __shfl_xor(lR[r], 8);
  }

  // ---- combine wave pairs, epilogue ----
  float* Ob = (float*)smem;  // 4 pairs x [16][256] fp32 = 64 KB (KT0+KT1)
  if (half == 1) {
#pragma unroll
    for (int dt = 0; dt < 16; ++dt)
#pragma unroll
      for (int r = 0; r < 4; ++r) {
        int row = hi * 4 + r;
        int byte = (row * 1024 + (dt * 16 + l15) * 4) ^ ((row & 15) << 6);
        *(float*)((char*)Ob + wg * 16384 + byte) = o[dt][r];
      }
    if (l15 == 0) {
#pragma unroll
      for (int r = 0; r < 4; ++r)
        Cm[wg * 16 + hi * 4 + r] = lR[r];
    }
  }
  __syncthreads();
  if (half == 0) {
#pragma unroll
    for (int r = 0; r < 4; ++r) {
      int rowl = hi * 4 + r;
      float inv = 1.f / (lR[r] + Cm[wg * 16 + rowl]);
      int orow = b * 1024 + q0 + wg * 16 + rowl;
#pragma unroll
      for (int dt = 0; dt < 16; ++dt) {
        int byte = (rowl * 1024 + (dt * 16 + l15) * 4) ^ ((rowl & 15) << 6);
        float ob = *(const float*)((const char*)Ob + wg * 16384 + byte);
        float v = (o[dt][r] + ob) * inv;
        out[orow * 256 + dt * 16 + l15] = fmaxf(v, 0.f);
      }
    }
  }
#undef STAGE_TILE
}

// ---------------------------------------------------------------------------
extern "C" void kernel_launch(void* const* d_in, const int* in_sizes, int n_in,
                              void* d_out, int out_size, void* d_ws,
                              size_t ws_size, hipStream_t stream) {
  const float* feature = (const float*)d_in[0];
  const int* graph = (const int*)d_in[1];
  const float* W_w = (const float*)d_in[2];
  const float* W_b = (const float*)d_in[3];
  const float* Q_w = (const float*)d_in[4];
  const float* Q_b = (const float*)d_in[5];
  const float* K_w = (const float*)d_in[6];
  const float* K_b = (const float*)d_in[7];
  float* out = (float*)d_out;

  ushort* hT = (ushort*)d_ws;         // [B,D,N] bf16   8 MB
  ushort* q = hT + MTOT * DD;         // [B,N,D] bf16   8 MB
  ushort* k = q + MTOT * DD;          // [B,N,D] bf16   8 MB

  gemm_fused<<<256, 256, 0, stream>>>(feature, W_w, W_b, Q_w, Q_b, K_w, K_b,
                                      hT, q, k);
  attn8<<<256, 512, 0, stream>>>(q, k, hT, graph, out);
}

// Round 25
// 80.966 us; speedup vs baseline: 3.0659x; 1.1257x over previous
//
#include <hip/hip_runtime.h>
#include <hip/hip_bf16.h>
#include <stdint.h>

#define DD 256
#define NB 16
#define NN 1024
#define MTOT (NB * NN)  // 16384

typedef __attribute__((ext_vector_type(8))) short short8;
typedef __attribute__((ext_vector_type(4))) float f32x4;

__device__ __forceinline__ ushort f2b(float f) {
  uint32_t u = __float_as_uint(f);
  return (ushort)((u + 0x7fffu + ((u >> 16) & 1u)) >> 16);
}

// ---------------------------------------------------------------------------
// Preconvert the three 256x256 fp32 weight matrices to bf16 (row-major).
// 49152 threads x 4 elements. Removes all f2b VALU work from gemm staging.
__global__ __launch_bounds__(256) void wconv(const float* __restrict__ W_w,
                                             const float* __restrict__ Q_w,
                                             const float* __restrict__ K_w,
                                             ushort* __restrict__ wbf) {
  int idx4 = blockIdx.x * blockDim.x + threadIdx.x;  // [0, 49152)
  int m = idx4 >> 14;          // matrix index 0..2
  int off = idx4 & 16383;      // float4 index within matrix
  const float* src = (m == 0) ? W_w : (m == 1) ? Q_w : K_w;
  float4 v = ((const float4*)src)[off];
  ushort4 b4;
  b4.x = f2b(v.x); b4.y = f2b(v.y); b4.z = f2b(v.z); b4.w = f2b(v.w);
  ((ushort4*)(wbf + m * 65536))[off] = b4;
}

// Stage a preconverted 256x256 bf16 weight matrix into LDS, XOR-swizzled.
// Pure uint4 copy: 32 iterations, no conversion VALU.
__device__ __forceinline__ void stage_wbf(const ushort* __restrict__ Wb,
                                          ushort* Wl, int tid) {
#pragma unroll
  for (int i = 0; i < 32; ++i) {
    int idx8 = i * 256 + tid;        // uint4 index (8 bf16)
    int row = idx8 >> 5;             // 32 uint4 per 256-elem row
    int col0 = (idx8 & 31) << 3;     // element col
    uint4 v = ((const uint4*)Wb)[idx8];
    int byte = (row * 512 + col0 * 2) ^ ((row & 7) << 4);
    *(uint4*)((char*)Wl + byte) = v;
  }
}

// ---------------------------------------------------------------------------
// Fused h/q/k GEMM. Round-13 structure; weights now arrive preconverted bf16.
__global__ __launch_bounds__(256, 1) void gemm_fused(
    const float* __restrict__ feature, const ushort* __restrict__ wbf,
    const float* __restrict__ W_b, const float* __restrict__ Q_b,
    const float* __restrict__ K_b, ushort* __restrict__ hT,
    ushort* __restrict__ q, ushort* __restrict__ k) {
  __shared__ ushort Wl[256 * 256];  // 128 KB; doubles as Tl transpose buffer
  const int tid = threadIdx.x;
  const int w = tid >> 6, lane = tid & 63, l15 = lane & 15, hi = lane >> 4;
  const int m0 = blockIdx.x * 64 + w * 16;
  const int arow = m0 + l15;

  // ---- h = feature @ W_w^T + W_b ----
  stage_wbf(wbf, Wl, tid);
  __syncthreads();

  f32x4 acc[16] = {};
#pragma unroll
  for (int kk = 0; kk < 8; ++kk) {
    const int k0 = kk * 32 + hi * 8;
    const float4* ap = (const float4*)(feature + arow * 256 + k0);
    float4 x = ap[0], y = ap[1];
    short8 a;
    a[0] = (short)f2b(x.x); a[1] = (short)f2b(x.y);
    a[2] = (short)f2b(x.z); a[3] = (short)f2b(x.w);
    a[4] = (short)f2b(y.x); a[5] = (short)f2b(y.y);
    a[6] = (short)f2b(y.z); a[7] = (short)f2b(y.w);
#pragma unroll
    for (int et = 0; et < 16; ++et) {
      int er = et * 16 + l15;
      short8 bf = *(const short8*)((const char*)Wl +
                                   ((er * 512 + k0 * 2) ^ ((er & 7) << 4)));
      acc[et] = __builtin_amdgcn_mfma_f32_16x16x32_bf16(a, bf, acc[et], 0, 0, 0);
    }
  }

  ushort hvals[16][4];
#pragma unroll
  for (int et = 0; et < 16; ++et) {
    float bv = W_b[et * 16 + l15];
#pragma unroll
    for (int r = 0; r < 4; ++r) hvals[et][r] = f2b(acc[et][r] + bv);
  }

  // ---- transpose h into Tl(=Wl) [256][64] ----
  __syncthreads();  // all waves done reading Wl
  ushort* Tl = Wl;
  {
    const int mloc = w * 16 + hi * 4;
#pragma unroll
    for (int et = 0; et < 16; ++et)
#pragma unroll
      for (int r = 0; r < 4; ++r)
        Tl[(et * 16 + l15) * 64 + mloc + r] = hvals[et][r];
  }
  __syncthreads();

  // ---- (a) h A-frags back to registers; (b) hT to global ----
  short8 qa[8];
#pragma unroll
  for (int kk = 0; kk < 8; ++kk) {
    const int k0 = kk * 32 + hi * 8;
#pragma unroll
    for (int j = 0; j < 8; ++j)
      qa[kk][j] = (short)Tl[(k0 + j) * 64 + w * 16 + l15];
  }
  {
    const int bidx = blockIdx.x >> 4;
    const int n0 = (blockIdx.x & 15) * 64;
    ushort* dst = hT + bidx * (256 * 1024) + tid * 1024 + n0;
    const uint4* src = (const uint4*)(Tl + tid * 64);
#pragma unroll
    for (int j = 0; j < 8; ++j) ((uint4*)dst)[j] = src[j];
  }
  __syncthreads();  // Tl reads done before Q_w staging overwrites

  // ---- q = h @ Q_w^T + Q_b ----
  stage_wbf(wbf + 65536, Wl, tid);
  __syncthreads();
#pragma unroll
  for (int et = 0; et < 16; ++et) acc[et] = (f32x4){0.f, 0.f, 0.f, 0.f};
#pragma unroll
  for (int kk = 0; kk < 8; ++kk) {
    const int k0 = kk * 32 + hi * 8;
#pragma unroll
    for (int et = 0; et < 16; ++et) {
      int er = et * 16 + l15;
      short8 bf = *(const short8*)((const char*)Wl +
                                   ((er * 512 + k0 * 2) ^ ((er & 7) << 4)));
      acc[et] = __builtin_amdgcn_mfma_f32_16x16x32_bf16(qa[kk], bf, acc[et], 0, 0, 0);
    }
  }
#pragma unroll
  for (int et = 0; et < 16; ++et) {
    int e = et * 16 + l15;
    float bv = Q_b[e];
#pragma unroll
    for (int r = 0; r < 4; ++r)
      q[(m0 + hi * 4 + r) * 256 + e] = f2b(acc[et][r] + bv);
  }
  __syncthreads();  // q-compute reads of Wl done before K_w staging

  // ---- k = h @ K_w^T + K_b ----
  stage_wbf(wbf + 131072, Wl, tid);
  __syncthreads();
#pragma unroll
  for (int et = 0; et < 16; ++et) acc[et] = (f32x4){0.f, 0.f, 0.f, 0.f};
#pragma unroll
  for (int kk = 0; kk < 8; ++kk) {
    const int k0 = kk * 32 + hi * 8;
#pragma unroll
    for (int et = 0; et < 16; ++et) {
      int er = et * 16 + l15;
      short8 bf = *(const short8*)((const char*)Wl +
                                   ((er * 512 + k0 * 2) ^ ((er & 7) << 4)));
      acc[et] = __builtin_amdgcn_mfma_f32_16x16x32_bf16(qa[kk], bf, acc[et], 0, 0, 0);
    }
  }
#pragma unroll
  for (int et = 0; et < 16; ++et) {
    int e = et * 16 + l15;
    float bv = K_b[e];
#pragma unroll
    for (int r = 0; r < 4; ++r)
      k[(m0 + hi * 4 + r) * 256 + e] = f2b(acc[et][r] + bv);
  }
}

// ---------------------------------------------------------------------------
// Fused attention (round-24 winner, byte-identical): r10 inner compute,
// double-buffered staging, ONE barrier per tile.
#define SM_KT0 0       // ushort [64*256]  32768 B
#define SM_KT1 32768   // ushort [64*256]  32768 B
#define SM_HT0 65536   // ushort [256*64]  32768 B
#define SM_HT1 98304   // ushort [256*64]  32768 B
#define SM_PL 131072   // ushort Pl[8*16*32]  8192 B
#define SM_M2 139264   // uint   M2[2][128]   1024 B
#define SM_CM 140288   // float  Cm[64]        256 B
#define SM_SZ 140544

// P-buffer swizzle: XOR in bits>=4 keeps 16B blocks intact for ds_read_b128.
__device__ __forceinline__ int pswz(int row, int bytecol) {
  return (row * 64 + bytecol) ^ ((row & 7) << 4) ^ ((row >> 3) << 5);
}

__global__ __launch_bounds__(512, 2) void attn8(
    const ushort* __restrict__ Q, const ushort* __restrict__ Kb,
    const ushort* __restrict__ HT, const int* __restrict__ graph,
    float* __restrict__ out) {
  __shared__ __align__(16) char smem[SM_SZ];
  ushort* Pl = (ushort*)(smem + SM_PL);
  uint* M2 = (uint*)(smem + SM_M2);
  float* Cm = (float*)(smem + SM_CM);

  const int tid = threadIdx.x;
  const int w = tid >> 6, lane = tid & 63, l15 = lane & 15, hi = lane >> 4;
  const int wg = w >> 1, half = w & 1;
  // XCD-aware remap: XCD x handles batches {2x, 2x+1}
  const int hw = blockIdx.x;
  const int slot = hw >> 3;
  const int b = (hw & 7) * 2 + (slot >> 4);
  const int q0 = (slot & 15) * 64;
  const int qrow_a = q0 + wg * 16 + l15;
  const int qrow_cl = wg * 16 + hi * 4;  // local row base (+r)
  const int* grow_base = graph + (b * 1024 + q0 + w * 8) * 1024 + lane;

  int greg[8];

#define STAGE_TILE(tt, bb)                                                    \
  {                                                                           \
    ushort* Kd = (ushort*)(smem + ((bb) ? SM_KT1 : SM_KT0));                  \
    ushort* Hd = (ushort*)(smem + ((bb) ? SM_HT1 : SM_HT0));                  \
    _Pragma("unroll") for (int i = 0; i < 4; ++i) {                           \
      int c = i * 512 + tid;                                                  \
      int krow = c >> 5, col0 = (c & 31) << 3;                                \
      uint4 v =                                                               \
          *(const uint4*)(Kb + (b * 1024 + (tt) * 64 + krow) * 256 + col0);   \
      *(uint4*)((char*)Kd + ((krow * 512 + col0 * 2) ^ ((krow & 7) << 4))) =  \
          v;                                                                  \
    }                                                                         \
    _Pragma("unroll") for (int i = 0; i < 4; ++i) {                           \
      int c = i * 512 + tid;                                                  \
      int drow = c >> 3, col0 = (c & 7) << 3;                                 \
      uint4 v = *(const uint4*)(HT + b * (256 * 1024) + drow * 1024 +         \
                                (tt) * 64 + col0);                            \
      *(uint4*)((char*)Hd + ((drow * 128 + col0 * 2) ^ ((drow & 7) << 4))) =  \
          v;                                                                  \
    }                                                                         \
  }

  // ---- prologue: stage tile 0 into buf0; graph(0) ballot into M2[0] ----
#pragma unroll
  for (int j = 0; j < 8; ++j) greg[j] = grow_base[j * 1024];

  STAGE_TILE(0, 0);

  short8 qf[8];
#pragma unroll
  for (int kk = 0; kk < 8; ++kk)
    qf[kk] = *(const short8*)(Q + (b * 1024 + qrow_a) * 256 + kk * 32 + hi * 8);

#pragma unroll
  for (int j = 0; j < 8; ++j) {
    unsigned long long mm = __ballot(greg[j] != 0);
    if (lane == 0) {
      M2[(w * 8 + j) * 2] = (uint)mm;
      M2[(w * 8 + j) * 2 + 1] = (uint)(mm >> 32);
    }
  }

  float lR[4] = {0.f, 0.f, 0.f, 0.f};  // per-LANE partial row sums
  f32x4 o[16] = {};

  __syncthreads();  // tile 0 staged

  for (int t = 0; t < 16; ++t) {
    const int cur = t & 1;
    const ushort* Kt = (const ushort*)(smem + (cur ? SM_KT1 : SM_KT0));
    const ushort* Ht = (const ushort*)(smem + (cur ? SM_HT1 : SM_HT0));
    const uint* M2c = M2 + cur * 128;
    uint* M2n = M2 + (cur ^ 1) * 128;

    // issue next tile's graph loads NOW; compute covers the HBM latency
    if (t < 15) {
#pragma unroll
      for (int j = 0; j < 8; ++j) greg[j] = grow_base[j * 1024 + (t + 1) * 64];
    }

    // S = q @ k^T : 16 rows x 32 keys (this wave's half)
    f32x4 s[2] = {};
    __builtin_amdgcn_s_setprio(1);
#pragma unroll
    for (int kk = 0; kk < 8; ++kk) {
#pragma unroll
      for (int nt = 0; nt < 2; ++nt) {
        int krow = half * 32 + nt * 16 + l15;
        short8 kf = *(const short8*)((const char*)Kt +
            ((krow * 512 + (kk * 32 + hi * 8) * 2) ^ ((krow & 7) << 4)));
        s[nt] = __builtin_amdgcn_mfma_f32_16x16x32_bf16(qf[kk], kf, s[nt], 0, 0, 0);
      }
    }
    __builtin_amdgcn_s_setprio(0);

    // scale, leaky, mask, exp — per-lane VALU only
    float p[2][4];
#pragma unroll
    for (int r = 0; r < 4; ++r) {
      uint mw = M2c[(qrow_cl + r) * 2 + half];
      float v0 = s[0][r] * 0.0625f; v0 = (v0 >= 0.f) ? v0 : 0.2f * v0;
      float v1 = s[1][r] * 0.0625f; v1 = (v1 >= 0.f) ? v1 : 0.2f * v1;
      float p0 = ((mw >> l15) & 1u) ? __expf(v0) : 0.f;
      float p1 = ((mw >> (16 + l15)) & 1u) ? __expf(v1) : 0.f;
      p[0][r] = p0; p[1][r] = p1;
      lR[r] += p0 + p1;
    }

    // P (C-layout) -> per-wave LDS -> A-frag layout
    ushort* Pw = Pl + w * 512;
#pragma unroll
    for (int nt = 0; nt < 2; ++nt)
#pragma unroll
      for (int r = 0; r < 4; ++r) {
        int row = hi * 4 + r, col = nt * 16 + l15;
        *(ushort*)((char*)Pw + pswz(row, col * 2)) = f2b(p[nt][r]);
      }
    __asm__ volatile("s_waitcnt lgkmcnt(0)" ::: "memory");
    short8 pa = *(const short8*)((const char*)Pw + pswz(l15, hi * 16));

    // O += P @ H (keys half*32 .. half*32+31)
    __builtin_amdgcn_s_setprio(1);
#pragma unroll
    for (int dt = 0; dt < 16; ++dt) {
      int dcol = dt * 16 + l15;
      short8 hf = *(const short8*)((const char*)Ht +
          ((dcol * 128 + (half * 32 + hi * 8) * 2) ^ ((dcol & 7) << 4)));
      o[dt] = __builtin_amdgcn_mfma_f32_16x16x32_bf16(pa, hf, o[dt], 0, 0, 0);
    }
    __builtin_amdgcn_s_setprio(0);

    if (t < 15) {
      // ballot next tile's mask into the other parity
#pragma unroll
      for (int j = 0; j < 8; ++j) {
        unsigned long long mm = __ballot(greg[j] != 0);
        if (lane == 0) {
          M2n[(w * 8 + j) * 2] = (uint)mm;
          M2n[(w * 8 + j) * 2 + 1] = (uint)(mm >> 32);
        }
      }
      // stage next tile into the other buffer
      STAGE_TILE(t + 1, cur ^ 1);
    }

    __syncthreads();  // single barrier per tile
  }

  // ---- reduce row sums once (16-lane groups share a row set) ----
#pragma unroll
  for (int r = 0; r < 4; ++r) {
    lR[r] += __shfl_xor(lR[r], 1);
    lR[r] += __shfl_xor(lR[r], 2);
    lR[r] += __shfl_xor(lR[r], 4);
    lR[r] += __shfl_xor(lR[r], 8);
  }

  // ---- combine wave pairs, epilogue ----
  float* Ob = (float*)smem;  // 4 pairs x [16][256] fp32 = 64 KB (KT0+KT1)
  if (half == 1) {
#pragma unroll
    for (int dt = 0; dt < 16; ++dt)
#pragma unroll
      for (int r = 0; r < 4; ++r) {
        int row = hi * 4 + r;
        int byte = (row * 1024 + (dt * 16 + l15) * 4) ^ ((row & 15) << 6);
        *(float*)((char*)Ob + wg * 16384 + byte) = o[dt][r];
      }
    if (l15 == 0) {
#pragma unroll
      for (int r = 0; r < 4; ++r)
        Cm[wg * 16 + hi * 4 + r] = lR[r];
    }
  }
  __syncthreads();
  if (half == 0) {
#pragma unroll
    for (int r = 0; r < 4; ++r) {
      int rowl = hi * 4 + r;
      float inv = 1.f / (lR[r] + Cm[wg * 16 + rowl]);
      int orow = b * 1024 + q0 + wg * 16 + rowl;
#pragma unroll
      for (int dt = 0; dt < 16; ++dt) {
        int byte = (rowl * 1024 + (dt * 16 + l15) * 4) ^ ((rowl & 15) << 6);
        float ob = *(const float*)((const char*)Ob + wg * 16384 + byte);
        float v = (o[dt][r] + ob) * inv;
        out[orow * 256 + dt * 16 + l15] = fmaxf(v, 0.f);
      }
    }
  }
#undef STAGE_TILE
}

// ---------------------------------------------------------------------------
extern "C" void kernel_launch(void* const* d_in, const int* in_sizes, int n_in,
                              void* d_out, int out_size, void* d_ws,
                              size_t ws_size, hipStream_t stream) {
  const float* feature = (const float*)d_in[0];
  const int* graph = (const int*)d_in[1];
  const float* W_w = (const float*)d_in[2];
  const float* W_b = (const float*)d_in[3];
  const float* Q_w = (const float*)d_in[4];
  const float* Q_b = (const float*)d_in[5];
  const float* K_w = (const float*)d_in[6];
  const float* K_b = (const float*)d_in[7];
  float* out = (float*)d_out;

  ushort* hT = (ushort*)d_ws;         // [B,D,N] bf16   8 MB
  ushort* q = hT + MTOT * DD;         // [B,N,D] bf16   8 MB
  ushort* k = q + MTOT * DD;          // [B,N,D] bf16   8 MB
  ushort* wbf = k + MTOT * DD;        // [3][256*256] bf16  384 KB

  wconv<<<192, 256, 0, stream>>>(W_w, Q_w, K_w, wbf);
  gemm_fused<<<256, 256, 0, stream>>>(feature, wbf, W_b, Q_b, K_b, hT, q, k);
  attn8<<<256, 512, 0, stream>>>(q, k, hT, graph, out);
}

// Round 26
// 80.937 us; speedup vs baseline: 3.0670x; 1.0004x over previous
//
#include <hip/hip_runtime.h>
#include <hip/hip_bf16.h>
#include <stdint.h>

#define DD 256
#define NB 16
#define NN 1024
#define MTOT (NB * NN)  // 16384

typedef __attribute__((ext_vector_type(8))) short short8;
typedef __attribute__((ext_vector_type(4))) float f32x4;

__device__ __forceinline__ ushort f2b(float f) {
  uint32_t u = __float_as_uint(f);
  return (ushort)((u + 0x7fffu + ((u >> 16) & 1u)) >> 16);
}

// ---------------------------------------------------------------------------
// Preconvert the three 256x256 fp32 weight matrices to bf16 (row-major).
__global__ __launch_bounds__(256) void wconv(const float* __restrict__ W_w,
                                             const float* __restrict__ Q_w,
                                             const float* __restrict__ K_w,
                                             ushort* __restrict__ wbf) {
  int idx4 = blockIdx.x * blockDim.x + threadIdx.x;  // [0, 49152)
  int m = idx4 >> 14;          // matrix index 0..2
  int off = idx4 & 16383;      // float4 index within matrix
  const float* src = (m == 0) ? W_w : (m == 1) ? Q_w : K_w;
  float4 v = ((const float4*)src)[off];
  ushort4 b4;
  b4.x = f2b(v.x); b4.y = f2b(v.y); b4.z = f2b(v.z); b4.w = f2b(v.w);
  ((ushort4*)(wbf + m * 65536))[off] = b4;
}

// Stage a preconverted 256x256 bf16 weight matrix into LDS, XOR-swizzled.
__device__ __forceinline__ void stage_wbf(const ushort* __restrict__ Wb,
                                          ushort* Wl, int tid) {
#pragma unroll
  for (int i = 0; i < 32; ++i) {
    int idx8 = i * 256 + tid;        // uint4 index (8 bf16)
    int row = idx8 >> 5;             // 32 uint4 per 256-elem row
    int col0 = (idx8 & 31) << 3;     // element col
    uint4 v = ((const uint4*)Wb)[idx8];
    int byte = (row * 512 + col0 * 2) ^ ((row & 7) << 4);
    *(uint4*)((char*)Wl + byte) = v;
  }
}

// ---------------------------------------------------------------------------
// Fused h/q/k GEMM (round-25, unchanged).
__global__ __launch_bounds__(256, 1) void gemm_fused(
    const float* __restrict__ feature, const ushort* __restrict__ wbf,
    const float* __restrict__ W_b, const float* __restrict__ Q_b,
    const float* __restrict__ K_b, ushort* __restrict__ hT,
    ushort* __restrict__ q, ushort* __restrict__ k) {
  __shared__ ushort Wl[256 * 256];  // 128 KB; doubles as Tl transpose buffer
  const int tid = threadIdx.x;
  const int w = tid >> 6, lane = tid & 63, l15 = lane & 15, hi = lane >> 4;
  const int m0 = blockIdx.x * 64 + w * 16;
  const int arow = m0 + l15;

  // ---- h = feature @ W_w^T + W_b ----
  stage_wbf(wbf, Wl, tid);
  __syncthreads();

  f32x4 acc[16] = {};
#pragma unroll
  for (int kk = 0; kk < 8; ++kk) {
    const int k0 = kk * 32 + hi * 8;
    const float4* ap = (const float4*)(feature + arow * 256 + k0);
    float4 x = ap[0], y = ap[1];
    short8 a;
    a[0] = (short)f2b(x.x); a[1] = (short)f2b(x.y);
    a[2] = (short)f2b(x.z); a[3] = (short)f2b(x.w);
    a[4] = (short)f2b(y.x); a[5] = (short)f2b(y.y);
    a[6] = (short)f2b(y.z); a[7] = (short)f2b(y.w);
#pragma unroll
    for (int et = 0; et < 16; ++et) {
      int er = et * 16 + l15;
      short8 bf = *(const short8*)((const char*)Wl +
                                   ((er * 512 + k0 * 2) ^ ((er & 7) << 4)));
      acc[et] = __builtin_amdgcn_mfma_f32_16x16x32_bf16(a, bf, acc[et], 0, 0, 0);
    }
  }

  ushort hvals[16][4];
#pragma unroll
  for (int et = 0; et < 16; ++et) {
    float bv = W_b[et * 16 + l15];
#pragma unroll
    for (int r = 0; r < 4; ++r) hvals[et][r] = f2b(acc[et][r] + bv);
  }

  // ---- transpose h into Tl(=Wl) [256][64] ----
  __syncthreads();  // all waves done reading Wl
  ushort* Tl = Wl;
  {
    const int mloc = w * 16 + hi * 4;
#pragma unroll
    for (int et = 0; et < 16; ++et)
#pragma unroll
      for (int r = 0; r < 4; ++r)
        Tl[(et * 16 + l15) * 64 + mloc + r] = hvals[et][r];
  }
  __syncthreads();

  // ---- (a) h A-frags back to registers; (b) hT to global ----
  short8 qa[8];
#pragma unroll
  for (int kk = 0; kk < 8; ++kk) {
    const int k0 = kk * 32 + hi * 8;
#pragma unroll
    for (int j = 0; j < 8; ++j)
      qa[kk][j] = (short)Tl[(k0 + j) * 64 + w * 16 + l15];
  }
  {
    const int bidx = blockIdx.x >> 4;
    const int n0 = (blockIdx.x & 15) * 64;
    ushort* dst = hT + bidx * (256 * 1024) + tid * 1024 + n0;
    const uint4* src = (const uint4*)(Tl + tid * 64);
#pragma unroll
    for (int j = 0; j < 8; ++j) ((uint4*)dst)[j] = src[j];
  }
  __syncthreads();  // Tl reads done before Q_w staging overwrites

  // ---- q = h @ Q_w^T + Q_b ----
  stage_wbf(wbf + 65536, Wl, tid);
  __syncthreads();
#pragma unroll
  for (int et = 0; et < 16; ++et) acc[et] = (f32x4){0.f, 0.f, 0.f, 0.f};
#pragma unroll
  for (int kk = 0; kk < 8; ++kk) {
    const int k0 = kk * 32 + hi * 8;
#pragma unroll
    for (int et = 0; et < 16; ++et) {
      int er = et * 16 + l15;
      short8 bf = *(const short8*)((const char*)Wl +
                                   ((er * 512 + k0 * 2) ^ ((er & 7) << 4)));
      acc[et] = __builtin_amdgcn_mfma_f32_16x16x32_bf16(qa[kk], bf, acc[et], 0, 0, 0);
    }
  }
#pragma unroll
  for (int et = 0; et < 16; ++et) {
    int e = et * 16 + l15;
    float bv = Q_b[e];
#pragma unroll
    for (int r = 0; r < 4; ++r)
      q[(m0 + hi * 4 + r) * 256 + e] = f2b(acc[et][r] + bv);
  }
  __syncthreads();  // q-compute reads of Wl done before K_w staging

  // ---- k = h @ K_w^T + K_b ----
  stage_wbf(wbf + 131072, Wl, tid);
  __syncthreads();
#pragma unroll
  for (int et = 0; et < 16; ++et) acc[et] = (f32x4){0.f, 0.f, 0.f, 0.f};
#pragma unroll
  for (int kk = 0; kk < 8; ++kk) {
    const int k0 = kk * 32 + hi * 8;
#pragma unroll
    for (int et = 0; et < 16; ++et) {
      int er = et * 16 + l15;
      short8 bf = *(const short8*)((const char*)Wl +
                                   ((er * 512 + k0 * 2) ^ ((er & 7) << 4)));
      acc[et] = __builtin_amdgcn_mfma_f32_16x16x32_bf16(qa[kk], bf, acc[et], 0, 0, 0);
    }
  }
#pragma unroll
  for (int et = 0; et < 16; ++et) {
    int e = et * 16 + l15;
    float bv = K_b[e];
#pragma unroll
    for (int r = 0; r < 4; ++r)
      k[(m0 + hi * 4 + r) * 256 + e] = f2b(acc[et][r] + bv);
  }
}

// ---------------------------------------------------------------------------
// Fused attention: r24 double-buffered single-barrier structure + T14
// issue-early/write-late staging. Tile t+1's K/H^T global loads are issued
// into registers at the TOP of iteration t (compute covers the HBM/L2
// latency); the ds_writes to buf[cur^1] happen after PV. Race-free: the
// write target was last read in compute(t-1), two phases behind the barrier.
#define SM_KT0 0       // ushort [64*256]  32768 B
#define SM_KT1 32768   // ushort [64*256]  32768 B
#define SM_HT0 65536   // ushort [256*64]  32768 B
#define SM_HT1 98304   // ushort [256*64]  32768 B
#define SM_PL 131072   // ushort Pl[8*16*32]  8192 B
#define SM_M2 139264   // uint   M2[2][128]   1024 B
#define SM_CM 140288   // float  Cm[64]        256 B
#define SM_SZ 140544

// P-buffer swizzle: XOR in bits>=4 keeps 16B blocks intact for ds_read_b128.
__device__ __forceinline__ int pswz(int row, int bytecol) {
  return (row * 64 + bytecol) ^ ((row & 7) << 4) ^ ((row >> 3) << 5);
}

__global__ __launch_bounds__(512, 2) void attn8(
    const ushort* __restrict__ Q, const ushort* __restrict__ Kb,
    const ushort* __restrict__ HT, const int* __restrict__ graph,
    float* __restrict__ out) {
  __shared__ __align__(16) char smem[SM_SZ];
  ushort* Pl = (ushort*)(smem + SM_PL);
  uint* M2 = (uint*)(smem + SM_M2);
  float* Cm = (float*)(smem + SM_CM);

  const int tid = threadIdx.x;
  const int w = tid >> 6, lane = tid & 63, l15 = lane & 15, hi = lane >> 4;
  const int wg = w >> 1, half = w & 1;
  // XCD-aware remap: XCD x handles batches {2x, 2x+1}
  const int hw = blockIdx.x;
  const int slot = hw >> 3;
  const int b = (hw & 7) * 2 + (slot >> 4);
  const int q0 = (slot & 15) * 64;
  const int qrow_a = q0 + wg * 16 + l15;
  const int qrow_cl = wg * 16 + hi * 4;  // local row base (+r)
  const int* grow_base = graph + (b * 1024 + q0 + w * 8) * 1024 + lane;

  int greg[8];
  uint4 kreg[4], hreg[4];

  // issue tile tt's K/H^T global loads into registers (no LDS writes)
#define STAGE_ISSUE(tt)                                                       \
  {                                                                           \
    _Pragma("unroll") for (int i = 0; i < 4; ++i) {                           \
      int c = i * 512 + tid;                                                  \
      int krow = c >> 5, col0 = (c & 31) << 3;                                \
      kreg[i] =                                                               \
          *(const uint4*)(Kb + (b * 1024 + (tt) * 64 + krow) * 256 + col0);   \
    }                                                                         \
    _Pragma("unroll") for (int i = 0; i < 4; ++i) {                           \
      int c = i * 512 + tid;                                                  \
      int drow = c >> 3, col0 = (c & 7) << 3;                                 \
      hreg[i] = *(const uint4*)(HT + b * (256 * 1024) + drow * 1024 +         \
                                (tt) * 64 + col0);                            \
    }                                                                         \
  }

  // write the staged registers into buffer pair bb, swizzled (r10 layout)
#define STAGE_WRITE(bb)                                                       \
  {                                                                           \
    ushort* Kd = (ushort*)(smem + ((bb) ? SM_KT1 : SM_KT0));                  \
    ushort* Hd = (ushort*)(smem + ((bb) ? SM_HT1 : SM_HT0));                  \
    _Pragma("unroll") for (int i = 0; i < 4; ++i) {                           \
      int c = i * 512 + tid;                                                  \
      int krow = c >> 5, col0 = (c & 31) << 3;                                \
      *(uint4*)((char*)Kd + ((krow * 512 + col0 * 2) ^ ((krow & 7) << 4))) =  \
          kreg[i];                                                            \
    }                                                                         \
    _Pragma("unroll") for (int i = 0; i < 4; ++i) {                           \
      int c = i * 512 + tid;                                                  \
      int drow = c >> 3, col0 = (c & 7) << 3;                                 \
      *(uint4*)((char*)Hd + ((drow * 128 + col0 * 2) ^ ((drow & 7) << 4))) =  \
          hreg[i];                                                            \
    }                                                                         \
  }

  // ---- prologue: stage tile 0 into buf0; graph(0) ballot into M2[0] ----
#pragma unroll
  for (int j = 0; j < 8; ++j) greg[j] = grow_base[j * 1024];

  STAGE_ISSUE(0);
  STAGE_WRITE(0);

  short8 qf[8];
#pragma unroll
  for (int kk = 0; kk < 8; ++kk)
    qf[kk] = *(const short8*)(Q + (b * 1024 + qrow_a) * 256 + kk * 32 + hi * 8);

#pragma unroll
  for (int j = 0; j < 8; ++j) {
    unsigned long long mm = __ballot(greg[j] != 0);
    if (lane == 0) {
      M2[(w * 8 + j) * 2] = (uint)mm;
      M2[(w * 8 + j) * 2 + 1] = (uint)(mm >> 32);
    }
  }

  float lR[4] = {0.f, 0.f, 0.f, 0.f};  // per-LANE partial row sums
  f32x4 o[16] = {};

  __syncthreads();  // tile 0 staged

  for (int t = 0; t < 16; ++t) {
    const int cur = t & 1;
    const ushort* Kt = (const ushort*)(smem + (cur ? SM_KT1 : SM_KT0));
    const ushort* Ht = (const ushort*)(smem + (cur ? SM_HT1 : SM_HT0));
    const uint* M2c = M2 + cur * 128;
    uint* M2n = M2 + (cur ^ 1) * 128;

    // issue next tile's loads NOW; compute covers the HBM/L2 latency
    if (t < 15) {
      STAGE_ISSUE(t + 1);
#pragma unroll
      for (int j = 0; j < 8; ++j) greg[j] = grow_base[j * 1024 + (t + 1) * 64];
    }

    // S = q @ k^T : 16 rows x 32 keys (this wave's half)
    f32x4 s[2] = {};
    __builtin_amdgcn_s_setprio(1);
#pragma unroll
    for (int kk = 0; kk < 8; ++kk) {
#pragma unroll
      for (int nt = 0; nt < 2; ++nt) {
        int krow = half * 32 + nt * 16 + l15;
        short8 kf = *(const short8*)((const char*)Kt +
            ((krow * 512 + (kk * 32 + hi * 8) * 2) ^ ((krow & 7) << 4)));
        s[nt] = __builtin_amdgcn_mfma_f32_16x16x32_bf16(qf[kk], kf, s[nt], 0, 0, 0);
      }
    }
    __builtin_amdgcn_s_setprio(0);

    // scale, leaky, mask, exp — per-lane VALU only
    float p[2][4];
#pragma unroll
    for (int r = 0; r < 4; ++r) {
      uint mw = M2c[(qrow_cl + r) * 2 + half];
      float v0 = s[0][r] * 0.0625f; v0 = (v0 >= 0.f) ? v0 : 0.2f * v0;
      float v1 = s[1][r] * 0.0625f; v1 = (v1 >= 0.f) ? v1 : 0.2f * v1;
      float p0 = ((mw >> l15) & 1u) ? __expf(v0) : 0.f;
      float p1 = ((mw >> (16 + l15)) & 1u) ? __expf(v1) : 0.f;
      p[0][r] = p0; p[1][r] = p1;
      lR[r] += p0 + p1;
    }

    // P (C-layout) -> per-wave LDS -> A-frag layout
    ushort* Pw = Pl + w * 512;
#pragma unroll
    for (int nt = 0; nt < 2; ++nt)
#pragma unroll
      for (int r = 0; r < 4; ++r) {
        int row = hi * 4 + r, col = nt * 16 + l15;
        *(ushort*)((char*)Pw + pswz(row, col * 2)) = f2b(p[nt][r]);
      }
    __asm__ volatile("s_waitcnt lgkmcnt(0)" ::: "memory");
    short8 pa = *(const short8*)((const char*)Pw + pswz(l15, hi * 16));

    // O += P @ H (keys half*32 .. half*32+31)
    __builtin_amdgcn_s_setprio(1);
#pragma unroll
    for (int dt = 0; dt < 16; ++dt) {
      int dcol = dt * 16 + l15;
      short8 hf = *(const short8*)((const char*)Ht +
          ((dcol * 128 + (half * 32 + hi * 8) * 2) ^ ((dcol & 7) << 4)));
      o[dt] = __builtin_amdgcn_mfma_f32_16x16x32_bf16(pa, hf, o[dt], 0, 0, 0);
    }
    __builtin_amdgcn_s_setprio(0);

    if (t < 15) {
      // ballot next tile's mask into the other parity
#pragma unroll
      for (int j = 0; j < 8; ++j) {
        unsigned long long mm = __ballot(greg[j] != 0);
        if (lane == 0) {
          M2n[(w * 8 + j) * 2] = (uint)mm;
          M2n[(w * 8 + j) * 2 + 1] = (uint)(mm >> 32);
        }
      }
      // land the staged registers into the other buffer (loads completed
      // during compute; only the ds_writes remain before the barrier)
      STAGE_WRITE(cur ^ 1);
    }

    __syncthreads();  // single barrier per tile
  }

  // ---- reduce row sums once (16-lane groups share a row set) ----
#pragma unroll
  for (int r = 0; r < 4; ++r) {
    lR[r] += __shfl_xor(lR[r], 1);
    lR[r] += __shfl_xor(lR[r], 2);
    lR[r] += __shfl_xor(lR[r], 4);
    lR[r] += __shfl_xor(lR[r], 8);
  }

  // ---- combine wave pairs, epilogue ----
  float* Ob = (float*)smem;  // 4 pairs x [16][256] fp32 = 64 KB (KT0+KT1)
  if (half == 1) {
#pragma unroll
    for (int dt = 0; dt < 16; ++dt)
#pragma unroll
      for (int r = 0; r < 4; ++r) {
        int row = hi * 4 + r;
        int byte = (row * 1024 + (dt * 16 + l15) * 4) ^ ((row & 15) << 6);
        *(float*)((char*)Ob + wg * 16384 + byte) = o[dt][r];
      }
    if (l15 == 0) {
#pragma unroll
      for (int r = 0; r < 4; ++r)
        Cm[wg * 16 + hi * 4 + r] = lR[r];
    }
  }
  __syncthreads();
  if (half == 0) {
#pragma unroll
    for (int r = 0; r < 4; ++r) {
      int rowl = hi * 4 + r;
      float inv = 1.f / (lR[r] + Cm[wg * 16 + rowl]);
      int orow = b * 1024 + q0 + wg * 16 + rowl;
#pragma unroll
      for (int dt = 0; dt < 16; ++dt) {
        int byte = (rowl * 1024 + (dt * 16 + l15) * 4) ^ ((rowl & 15) << 6);
        float ob = *(const float*)((const char*)Ob + wg * 16384 + byte);
        float v = (o[dt][r] + ob) * inv;
        out[orow * 256 + dt * 16 + l15] = fmaxf(v, 0.f);
      }
    }
  }
#undef STAGE_ISSUE
#undef STAGE_WRITE
}

// ---------------------------------------------------------------------------
extern "C" void kernel_launch(void* const* d_in, const int* in_sizes, int n_in,
                              void* d_out, int out_size, void* d_ws,
                              size_t ws_size, hipStream_t stream) {
  const float* feature = (const float*)d_in[0];
  const int* graph = (const int*)d_in[1];
  const float* W_w = (const float*)d_in[2];
  const float* W_b = (const float*)d_in[3];
  const float* Q_w = (const float*)d_in[4];
  const float* Q_b = (const float*)d_in[5];
  const float* K_w = (const float*)d_in[6];
  const float* K_b = (const float*)d_in[7];
  float* out = (float*)d_out;

  ushort* hT = (ushort*)d_ws;         // [B,D,N] bf16   8 MB
  ushort* q = hT + MTOT * DD;         // [B,N,D] bf16   8 MB
  ushort* k = q + MTOT * DD;          // [B,N,D] bf16   8 MB
  ushort* wbf = k + MTOT * DD;        // [3][256*256] bf16  384 KB

  wconv<<<192, 256, 0, stream>>>(W_w, Q_w, K_w, wbf);
  gemm_fused<<<256, 256, 0, stream>>>(feature, wbf, W_b, Q_b, K_b, hT, q, k);
  attn8<<<256, 512, 0, stream>>>(q, k, hT, graph, out);
}